// Round 6
// baseline (315.403 us; speedup 1.0000x reference)
//
#include <hip/hip_runtime.h>
#include <hip/hip_bf16.h>

typedef float f32x4 __attribute__((ext_vector_type(4)));
typedef short bf16x8 __attribute__((ext_vector_type(8)));

#define MFMA_BF16 __builtin_amdgcn_mfma_f32_16x16x32_bf16

static __device__ __forceinline__ unsigned short f2bf(float f) {
    __hip_bfloat16 h = __float2bfloat16(f);
    return __builtin_bit_cast(unsigned short, h);
}
static __device__ __forceinline__ unsigned int pack2(float a, float b) {
    return (unsigned int)f2bf(a) | ((unsigned int)f2bf(b) << 16);
}

// Async global->LDS, 16B per lane. LDS dest is wave-uniform base + lane*16.
static __device__ __forceinline__ void gl16(const unsigned short* g, unsigned short* l) {
    unsigned short* gg = const_cast<unsigned short*>(g);
    __builtin_amdgcn_global_load_lds(
        (__attribute__((address_space(1))) unsigned int*)gg,
        (__attribute__((address_space(3))) unsigned int*)l, 16, 0, 0);
}

// ---------------------------------------------------------------------------
// Prep 1: W [1024][1024] f32 (k-major) -> Wt [1024][1024] bf16 (n-major, k-contig)
// ---------------------------------------------------------------------------
__global__ __launch_bounds__(256) void conv_wT(
    const float* __restrict__ Wq, const float* __restrict__ Wk,
    const float* __restrict__ Wv, const float* __restrict__ Wo,
    unsigned short* __restrict__ WT)
{
    const int z = blockIdx.z;
    const float* W = (z == 0) ? Wq : (z == 1) ? Wk : (z == 2) ? Wv : Wo;
    unsigned short* Wt = WT + (size_t)z * 1048576;
    const int k0 = blockIdx.x * 64, n0 = blockIdx.y * 64;
    __shared__ float tl[64][68];
    const int t = threadIdx.x;
    const int r = t >> 2, cs = (t & 3) * 16;
#pragma unroll
    for (int j = 0; j < 4; j++)
        *(float4*)&tl[r][cs + j * 4] = *(const float4*)&W[(size_t)(k0 + r) * 1024 + n0 + cs + j * 4];
    __syncthreads();
    const int n = t & 63, kb = (t >> 6) * 16;
#pragma unroll
    for (int j = 0; j < 4; j++) {
        const int kk = kb + j * 4;
        uint2 o = { pack2(tl[kk][n], tl[kk + 1][n]), pack2(tl[kk + 2][n], tl[kk + 3][n]) };
        *(uint2*)&Wt[(size_t)(n0 + n) * 1024 + k0 + kk] = o;
    }
}

// ---------------------------------------------------------------------------
// Prep 2: q/k/v f32 -> bf16. grid (2048, 3).
// ---------------------------------------------------------------------------
__global__ __launch_bounds__(256) void conv_bf16(
    const float* __restrict__ q, const float* __restrict__ k, const float* __restrict__ v,
    unsigned short* __restrict__ qkvb)
{
    const int z = blockIdx.y;
    const float* s = (z == 0) ? q : (z == 1) ? k : v;
    unsigned short* d = qkvb + (size_t)z * 4194304;
    const size_t i = ((size_t)blockIdx.x * 256 + threadIdx.x) * 8;
    float4 a = *(const float4*)&s[i], b = *(const float4*)&s[i + 4];
    uint4 o = { pack2(a.x, a.y), pack2(a.z, a.w), pack2(b.x, b.y), pack2(b.z, b.w) };
    *(uint4*)&d[i] = o;
}

// ---------------------------------------------------------------------------
// Shared GEMM core: C(128x128) = A(row-major [M][1024] bf16) x Bt^T
// ---------------------------------------------------------------------------
static __device__ __forceinline__ void gemm_core(
    const unsigned short* __restrict__ A, const unsigned short* __restrict__ Bt,
    unsigned short* lA, unsigned short* lB, int m0, int n0, f32x4 (&acc)[4][4])
{
    const int t = threadIdx.x;
    const int w = t >> 6, lane = t & 63, lrow = lane & 15, lkg = lane >> 4;
    const int wr = w >> 1, wc = w & 1;
    const int srow = lane >> 2, sseg = (lane & 3) * 8;

    for (int k0 = 0; k0 < 1024; k0 += 32) {
        gl16(&A[(size_t)(m0 + w * 32 + srow) * 1024 + k0 + sseg], &lA[w * 1024]);
        gl16(&A[(size_t)(m0 + w * 32 + 16 + srow) * 1024 + k0 + sseg], &lA[w * 1024 + 512]);
        gl16(&Bt[(size_t)(n0 + w * 32 + srow) * 1024 + k0 + sseg], &lB[w * 1024]);
        gl16(&Bt[(size_t)(n0 + w * 32 + 16 + srow) * 1024 + k0 + sseg], &lB[w * 1024 + 512]);
        __syncthreads();
        bf16x8 af[4], bfr[4];
#pragma unroll
        for (int mi = 0; mi < 4; mi++)
            af[mi] = *(const bf16x8*)&lA[(wr * 64 + mi * 16 + lrow) * 32 + lkg * 8];
#pragma unroll
        for (int ni = 0; ni < 4; ni++)
            bfr[ni] = *(const bf16x8*)&lB[(wc * 64 + ni * 16 + lrow) * 32 + lkg * 8];
#pragma unroll
        for (int mi = 0; mi < 4; mi++)
#pragma unroll
            for (int ni = 0; ni < 4; ni++)
                acc[mi][ni] = MFMA_BF16(af[mi], bfr[ni], acc[mi][ni], 0, 0, 0);
        __syncthreads();
    }
}

// ---------------------------------------------------------------------------
// QKV projections. z=0: Q->[B,H,L,64]; z=1: K->[B,H,L,64]; z=2: V->[B,H,64,L].
// ---------------------------------------------------------------------------
__global__ __launch_bounds__(256) void gemm_qkv(
    const unsigned short* __restrict__ qkvb, const unsigned short* __restrict__ WT,
    const float* __restrict__ bq, const float* __restrict__ bk, const float* __restrict__ bv,
    unsigned short* __restrict__ Qh, unsigned short* __restrict__ Kh, unsigned short* __restrict__ Vt)
{
    const int z = blockIdx.z;
    const unsigned short* A = qkvb + (size_t)z * 4194304;
    const unsigned short* Bt = WT + (size_t)z * 1048576;
    const float* bias = (z == 0) ? bq : (z == 1) ? bk : bv;

    const int n0 = blockIdx.x * 128, m0 = blockIdx.y * 128;
    __shared__ unsigned short lA[4096], lB[4096];
    f32x4 acc[4][4];
#pragma unroll
    for (int i = 0; i < 4; i++)
#pragma unroll
        for (int j = 0; j < 4; j++) acc[i][j] = (f32x4){0.f, 0.f, 0.f, 0.f};

    gemm_core(A, Bt, lA, lB, m0, n0, acc);

    const int t = threadIdx.x;
    const int w = t >> 6, lane = t & 63, lrow = lane & 15, lkg = lane >> 4;
    const int wr = w >> 1, wc = w & 1;

#pragma unroll
    for (int mi = 0; mi < 4; mi++) {
#pragma unroll
        for (int ni = 0; ni < 4; ni++) {
            const int gn = n0 + wc * 64 + ni * 16 + lrow;
            const float bb = bias[gn];
            const int hh = gn >> 6, dk = gn & 63;
            const int gm0 = m0 + wr * 64 + mi * 16 + lkg * 4;
            const int b2 = gm0 >> 11, ll = gm0 & 2047;
            if (z < 2) {
                unsigned short* C = (z == 0) ? Qh : Kh;
#pragma unroll
                for (int r = 0; r < 4; r++)
                    C[(size_t)((b2 * 16 + hh) * 2048 + ll + r) * 64 + dk] = f2bf(acc[mi][ni][r] + bb);
            } else {
                uint2 o = { pack2(acc[mi][ni][0] + bb, acc[mi][ni][1] + bb),
                            pack2(acc[mi][ni][2] + bb, acc[mi][ni][3] + bb) };
                *(uint2*)&Vt[(size_t)((b2 * 16 + hh) * 64 + dk) * 2048 + ll] = o;
            }
        }
    }
}

// ---------------------------------------------------------------------------
// Output projection: out_f32 = Oh_bf16 @ WoT^T + bo.
// ---------------------------------------------------------------------------
__global__ __launch_bounds__(256) void gemm_o(
    const unsigned short* __restrict__ Oh, const unsigned short* __restrict__ WoT,
    const float* __restrict__ bo, float* __restrict__ out)
{
    const int n0 = blockIdx.x * 128, m0 = blockIdx.y * 128;
    __shared__ unsigned short lA[4096], lB[4096];
    f32x4 acc[4][4];
#pragma unroll
    for (int i = 0; i < 4; i++)
#pragma unroll
        for (int j = 0; j < 4; j++) acc[i][j] = (f32x4){0.f, 0.f, 0.f, 0.f};

    gemm_core(Oh, WoT, lA, lB, m0, n0, acc);

    const int t = threadIdx.x;
    const int w = t >> 6, lane = t & 63, lrow = lane & 15, lkg = lane >> 4;
    const int wr = w >> 1, wc = w & 1;

#pragma unroll
    for (int mi = 0; mi < 4; mi++) {
#pragma unroll
        for (int ni = 0; ni < 4; ni++) {
            const int gn = n0 + wc * 64 + ni * 16 + lrow;
            const float bb = bo[gn];
            const int gm0 = m0 + wr * 64 + mi * 16 + lkg * 4;
#pragma unroll
            for (int r = 0; r < 4; r++)
                out[(size_t)(gm0 + r) * 1024 + gn] = acc[mi][ni][r] + bb;
        }
    }
}

// ---------------------------------------------------------------------------
// Fused attention. 8 waves x 16 q-rows (Q-tile 128).
// Per tile: { vmcnt(N); s_barrier; issue prefetch(t+1); compute(t) }.
// Sweep 1 (KVBLK=128, 16 tiles): N=0 (only own prefetch outstanding; it had
// a full compute phase to land). Sweep 2 (KVBLK=64, 32 tiles): N=4 retires
// exactly this tile's prefetch, leaves previous tile's 4 attn stores in
// flight. PLAIN stores (no nontemporal): each lane-quad writes a full
// aligned 64B line -> streams through L2 at fill-kernel BW.
// LDS: 2x16KB KV dbuf + 16KB lP = 48KB.
// ---------------------------------------------------------------------------
__global__ __launch_bounds__(512, 4) void attn_kernel(
    const unsigned short* __restrict__ Qh, const unsigned short* __restrict__ Kh,
    const unsigned short* __restrict__ Vt, float* __restrict__ attn,
    unsigned short* __restrict__ Oh)
{
    const int bid = blockIdx.x;
    const int swz = (bid & 7) * 64 + (bid >> 3);     // XCD-contiguous
    const int bh = swz >> 4;
    const int q0 = (swz & 15) * 128;
    const int b = bh >> 4, h = bh & 15;
    const int t = threadIdx.x;
    const int w = t >> 6, lane = t & 63, ql = lane & 15, kg = lane >> 4;

    __shared__ unsigned short lS[2][8192];   // dbuf: s1: K[128][8 slots]; s2: K[64][8] + V[64][8]
    __shared__ unsigned short lP[8192];      // per-wave [16 q][64 k], swizzled

    const size_t kvbase = (size_t)bh * 2048 * 64;
    const float C = 0.18033688011112042f;    // 0.125 * log2(e)

    const unsigned short* qptr = Qh + kvbase + (size_t)(q0 + w * 16 + ql) * 64 + kg * 8;
    const bf16x8 qf0 = *(const bf16x8*)(qptr);
    const bf16x8 qf1 = *(const bf16x8*)(qptr + 32);

    const unsigned short* Kbh = Kh + kvbase;
    const unsigned short* Vbh = Vt + kvbase;

    // staging coords: wave w covers rows w*8..w*8+7; source col16 pre-swizzled
    const int kr = w * 8 + (lane >> 3);
    const int kc = (lane & 7) ^ (kr & 7);
    const int r7 = ql & 7;

    // ---- sweep 1: denominators (K tiles of 128 rows, double-buffered) ----
    f32x4 ls4 = (f32x4){0.f, 0.f, 0.f, 0.f};
    // prologue: prefetch tile 0
    gl16(Kbh + (size_t)kr * 64 + kc * 8, &lS[0][w * 512]);
    gl16(Kbh + (size_t)(kr + 64) * 64 + kc * 8, &lS[0][4096 + w * 512]);
    __builtin_amdgcn_sched_barrier(0);

    for (int kt = 0; kt < 16; ++kt) {
        const int c = kt & 1;
        asm volatile("s_waitcnt vmcnt(0)" ::: "memory");
        __builtin_amdgcn_s_barrier();
        __builtin_amdgcn_sched_barrier(0);
        if (kt < 15) {
            const int k0n = (kt + 1) * 128;
            gl16(Kbh + (size_t)(k0n + kr) * 64 + kc * 8, &lS[c ^ 1][w * 512]);
            gl16(Kbh + (size_t)(k0n + kr + 64) * 64 + kc * 8, &lS[c ^ 1][4096 + w * 512]);
        } else {
            // prefetch sweep-2 tile 0 (K rows 0..63 + V cols 0..63) into lS[0]
            gl16(Kbh + (size_t)kr * 64 + kc * 8, &lS[0][w * 512]);
            gl16(Vbh + (size_t)kr * 2048 + kc * 8, &lS[0][4096 + w * 512]);
        }
        __builtin_amdgcn_sched_barrier(0);
        const unsigned short* Kl = lS[c];
        f32x4 sacc[8];
        __builtin_amdgcn_s_setprio(1);
#pragma unroll
        for (int ni = 0; ni < 8; ni++) {
            const int rb = (ni * 16 + ql) * 64;
            bf16x8 kf0 = *(const bf16x8*)&Kl[rb + ((kg ^ r7) * 8)];
            bf16x8 kf1 = *(const bf16x8*)&Kl[rb + (((4 + kg) ^ r7) * 8)];
            f32x4 s = (f32x4){0.f, 0.f, 0.f, 0.f};
            s = MFMA_BF16(kf0, qf0, s, 0, 0, 0);
            sacc[ni] = MFMA_BF16(kf1, qf1, s, 0, 0, 0);
        }
        __builtin_amdgcn_s_setprio(0);
#pragma unroll
        for (int ni = 0; ni < 8; ni++)
#pragma unroll
            for (int r = 0; r < 4; r++) ls4[r] += exp2f(sacc[ni][r] * C);
    }
    float lsum = ls4[0] + ls4[1] + ls4[2] + ls4[3];
    lsum += __shfl_xor(lsum, 16);
    lsum += __shfl_xor(lsum, 32);
    const float mlg = -log2f(lsum);          // p = exp2(S*C - log2 l)

    // ---- sweep 2: attn write + PV (K+V tiles of 64, double-buffered) ----
    f32x4 acco[4];
#pragma unroll
    for (int nv = 0; nv < 4; nv++) acco[nv] = (f32x4){0.f, 0.f, 0.f, 0.f};

    unsigned short* lPw = &lP[w * 1024];
    const int swz8 = r7 << 3;
    float* arow = attn + ((size_t)bh * 2048 + q0 + w * 16 + ql) * 2048;

    for (int kt = 0; kt < 32; ++kt) {
        const int c = kt & 1;
        if (kt == 0) { asm volatile("s_waitcnt vmcnt(0)" ::: "memory"); }
        else         { asm volatile("s_waitcnt vmcnt(4)" ::: "memory"); }
        __builtin_amdgcn_s_barrier();
        __builtin_amdgcn_sched_barrier(0);
        if (kt < 31) {
            const int k0n = (kt + 1) * 64;
            gl16(Kbh + (size_t)(k0n + kr) * 64 + kc * 8, &lS[c ^ 1][w * 512]);
            gl16(Vbh + (size_t)kr * 2048 + k0n + kc * 8, &lS[c ^ 1][4096 + w * 512]);
        }
        __builtin_amdgcn_sched_barrier(0);
        const int k0 = kt * 64;
        const unsigned short* Kl = lS[c];
        const unsigned short* Vl = &lS[c][4096];

        f32x4 sacc[4];
        __builtin_amdgcn_s_setprio(1);
#pragma unroll
        for (int ni = 0; ni < 4; ni++) {
            const int rb = (ni * 16 + ql) * 64;
            bf16x8 kf0 = *(const bf16x8*)&Kl[rb + ((kg ^ r7) * 8)];
            bf16x8 kf1 = *(const bf16x8*)&Kl[rb + (((4 + kg) ^ r7) * 8)];
            f32x4 s = (f32x4){0.f, 0.f, 0.f, 0.f};
            s = MFMA_BF16(kf0, qf0, s, 0, 0, 0);
            sacc[ni] = MFMA_BF16(kf1, qf1, s, 0, 0, 0);
        }
        __builtin_amdgcn_s_setprio(0);
#pragma unroll
        for (int ni = 0; ni < 4; ni++) {
            f32x4 p;
#pragma unroll
            for (int r = 0; r < 4; r++) p[r] = exp2f(fmaf(sacc[ni][r], C, mlg));
            uint2 pk = { pack2(p[0], p[1]), pack2(p[2], p[3]) };
            *(uint2*)&lPw[(ql * 64 + ni * 16 + kg * 4) ^ swz8] = pk;
            *(f32x4*)&arow[k0 + ni * 16 + kg * 4] = p;     // plain store (full 64B lines)
        }
        // PV: O^T += V^T x P^T
        __builtin_amdgcn_s_setprio(1);
#pragma unroll
        for (int s4 = 0; s4 < 2; s4++) {
            bf16x8 pf = *(const bf16x8*)&lPw[(ql * 64 + s4 * 32 + kg * 8) ^ swz8];
#pragma unroll
            for (int nv = 0; nv < 4; nv++) {
                const int cc = (s4 * 4 + kg) ^ r7;
                bf16x8 vf = *(const bf16x8*)&Vl[(nv * 16 + ql) * 64 + cc * 8];
                acco[nv] = MFMA_BF16(vf, pf, acco[nv], 0, 0, 0);
            }
        }
        __builtin_amdgcn_s_setprio(0);
    }

    unsigned short* obase = Oh + ((size_t)(b * 2048 + q0 + w * 16 + ql)) * 1024 + h * 64 + kg * 4;
#pragma unroll
    for (int nv = 0; nv < 4; nv++) {
        uint2 o2 = { pack2(acco[nv][0], acco[nv][1]), pack2(acco[nv][2], acco[nv][3]) };
        *(uint2*)&obase[nv * 16] = o2;
    }
}

// ---------------------------------------------------------------------------
extern "C" void kernel_launch(void* const* d_in, const int* in_sizes, int n_in,
                              void* d_out, int out_size, void* d_ws, size_t ws_size,
                              hipStream_t stream) {
    const float* q  = (const float*)d_in[0];
    const float* k  = (const float*)d_in[1];
    const float* v  = (const float*)d_in[2];
    const float* Wq = (const float*)d_in[3];
    const float* bq = (const float*)d_in[4];
    const float* Wk = (const float*)d_in[5];
    const float* bk = (const float*)d_in[6];
    const float* Wv = (const float*)d_in[7];
    const float* bv = (const float*)d_in[8];
    const float* Wo = (const float*)d_in[9];
    const float* bo = (const float*)d_in[10];

    float* out  = (float*)d_out;                    // [2,2048,1024]
    float* attn = out + (size_t)2 * 2048 * 1024;    // [2,16,2048,2048]

    const size_t HS = 4194304;                      // 2*16*2048*64
    unsigned short* qkvb = (unsigned short*)d_ws;   // 3*HS bf16
    unsigned short* WT   = qkvb + 3 * HS;           // 4 * 1M bf16
    unsigned short* Qh   = WT + 4 * 1048576;        // [B,H,L,64]
    unsigned short* Kh   = Qh + HS;                 // [B,H,L,64]
    unsigned short* Vt   = Kh + HS;                 // [B,H,64,L]
    unsigned short* Oh   = Vt + HS;                 // [B,L,1024]

    conv_wT  <<<dim3(16, 16, 4), 256, 0, stream>>>(Wq, Wk, Wv, Wo, WT);
    conv_bf16<<<dim3(2048, 3),  256, 0, stream>>>(q, k, v, qkvb);
    gemm_qkv <<<dim3(8, 32, 3), 256, 0, stream>>>(qkvb, WT, bq, bk, bv, Qh, Kh, Vt);
    attn_kernel<<<dim3(512), 512, 0, stream>>>(Qh, Kh, Vt, attn, Oh);
    gemm_o   <<<dim3(8, 32),   256, 0, stream>>>(Oh, WT + 3 * 1048576, bo, out);
}

// Round 7
// 268.222 us; speedup vs baseline: 1.1759x; 1.1759x over previous
//
#include <hip/hip_runtime.h>
#include <hip/hip_bf16.h>

typedef float f32x4 __attribute__((ext_vector_type(4)));
typedef short bf16x8 __attribute__((ext_vector_type(8)));

#define MFMA_BF16 __builtin_amdgcn_mfma_f32_16x16x32_bf16

static __device__ __forceinline__ unsigned short f2bf(float f) {
    __hip_bfloat16 h = __float2bfloat16(f);
    return __builtin_bit_cast(unsigned short, h);
}
static __device__ __forceinline__ unsigned int pack2(float a, float b) {
    return (unsigned int)f2bf(a) | ((unsigned int)f2bf(b) << 16);
}

// Async global->LDS, 16B per lane. LDS dest is wave-uniform base + lane*16.
static __device__ __forceinline__ void gl16(const unsigned short* g, unsigned short* l) {
    unsigned short* gg = const_cast<unsigned short*>(g);
    __builtin_amdgcn_global_load_lds(
        (__attribute__((address_space(1))) unsigned int*)gg,
        (__attribute__((address_space(3))) unsigned int*)l, 16, 0, 0);
}

// ---------------------------------------------------------------------------
// Prep 1: W [1024][1024] f32 (k-major) -> Wt [1024][1024] bf16 (n-major, k-contig)
// ---------------------------------------------------------------------------
__global__ __launch_bounds__(256) void conv_wT(
    const float* __restrict__ Wq, const float* __restrict__ Wk,
    const float* __restrict__ Wv, const float* __restrict__ Wo,
    unsigned short* __restrict__ WT)
{
    const int z = blockIdx.z;
    const float* W = (z == 0) ? Wq : (z == 1) ? Wk : (z == 2) ? Wv : Wo;
    unsigned short* Wt = WT + (size_t)z * 1048576;
    const int k0 = blockIdx.x * 64, n0 = blockIdx.y * 64;
    __shared__ float tl[64][68];
    const int t = threadIdx.x;
    const int r = t >> 2, cs = (t & 3) * 16;
#pragma unroll
    for (int j = 0; j < 4; j++)
        *(float4*)&tl[r][cs + j * 4] = *(const float4*)&W[(size_t)(k0 + r) * 1024 + n0 + cs + j * 4];
    __syncthreads();
    const int n = t & 63, kb = (t >> 6) * 16;
#pragma unroll
    for (int j = 0; j < 4; j++) {
        const int kk = kb + j * 4;
        uint2 o = { pack2(tl[kk][n], tl[kk + 1][n]), pack2(tl[kk + 2][n], tl[kk + 3][n]) };
        *(uint2*)&Wt[(size_t)(n0 + n) * 1024 + k0 + kk] = o;
    }
}

// ---------------------------------------------------------------------------
// Prep 2: q/k/v f32 -> bf16. grid (2048, 3).
// ---------------------------------------------------------------------------
__global__ __launch_bounds__(256) void conv_bf16(
    const float* __restrict__ q, const float* __restrict__ k, const float* __restrict__ v,
    unsigned short* __restrict__ qkvb)
{
    const int z = blockIdx.y;
    const float* s = (z == 0) ? q : (z == 1) ? k : v;
    unsigned short* d = qkvb + (size_t)z * 4194304;
    const size_t i = ((size_t)blockIdx.x * 256 + threadIdx.x) * 8;
    float4 a = *(const float4*)&s[i], b = *(const float4*)&s[i + 4];
    uint4 o = { pack2(a.x, a.y), pack2(a.z, a.w), pack2(b.x, b.y), pack2(b.z, b.w) };
    *(uint4*)&d[i] = o;
}

// ---------------------------------------------------------------------------
// Shared GEMM core: C(128x128) = A(row-major [M][1024] bf16) x Bt^T
// ---------------------------------------------------------------------------
static __device__ __forceinline__ void gemm_core(
    const unsigned short* __restrict__ A, const unsigned short* __restrict__ Bt,
    unsigned short* lA, unsigned short* lB, int m0, int n0, f32x4 (&acc)[4][4])
{
    const int t = threadIdx.x;
    const int w = t >> 6, lane = t & 63, lrow = lane & 15, lkg = lane >> 4;
    const int wr = w >> 1, wc = w & 1;
    const int srow = lane >> 2, sseg = (lane & 3) * 8;

    for (int k0 = 0; k0 < 1024; k0 += 32) {
        gl16(&A[(size_t)(m0 + w * 32 + srow) * 1024 + k0 + sseg], &lA[w * 1024]);
        gl16(&A[(size_t)(m0 + w * 32 + 16 + srow) * 1024 + k0 + sseg], &lA[w * 1024 + 512]);
        gl16(&Bt[(size_t)(n0 + w * 32 + srow) * 1024 + k0 + sseg], &lB[w * 1024]);
        gl16(&Bt[(size_t)(n0 + w * 32 + 16 + srow) * 1024 + k0 + sseg], &lB[w * 1024 + 512]);
        __syncthreads();
        bf16x8 af[4], bfr[4];
#pragma unroll
        for (int mi = 0; mi < 4; mi++)
            af[mi] = *(const bf16x8*)&lA[(wr * 64 + mi * 16 + lrow) * 32 + lkg * 8];
#pragma unroll
        for (int ni = 0; ni < 4; ni++)
            bfr[ni] = *(const bf16x8*)&lB[(wc * 64 + ni * 16 + lrow) * 32 + lkg * 8];
#pragma unroll
        for (int mi = 0; mi < 4; mi++)
#pragma unroll
            for (int ni = 0; ni < 4; ni++)
                acc[mi][ni] = MFMA_BF16(af[mi], bfr[ni], acc[mi][ni], 0, 0, 0);
        __syncthreads();
    }
}

// ---------------------------------------------------------------------------
// QKV projections. z=0: Q->[B,H,L,64]; z=1: K->[B,H,L,64]; z=2: V->[B,H,64,L].
// ---------------------------------------------------------------------------
__global__ __launch_bounds__(256) void gemm_qkv(
    const unsigned short* __restrict__ qkvb, const unsigned short* __restrict__ WT,
    const float* __restrict__ bq, const float* __restrict__ bk, const float* __restrict__ bv,
    unsigned short* __restrict__ Qh, unsigned short* __restrict__ Kh, unsigned short* __restrict__ Vt)
{
    const int z = blockIdx.z;
    const unsigned short* A = qkvb + (size_t)z * 4194304;
    const unsigned short* Bt = WT + (size_t)z * 1048576;
    const float* bias = (z == 0) ? bq : (z == 1) ? bk : bv;

    const int n0 = blockIdx.x * 128, m0 = blockIdx.y * 128;
    __shared__ unsigned short lA[4096], lB[4096];
    f32x4 acc[4][4];
#pragma unroll
    for (int i = 0; i < 4; i++)
#pragma unroll
        for (int j = 0; j < 4; j++) acc[i][j] = (f32x4){0.f, 0.f, 0.f, 0.f};

    gemm_core(A, Bt, lA, lB, m0, n0, acc);

    const int t = threadIdx.x;
    const int w = t >> 6, lane = t & 63, lrow = lane & 15, lkg = lane >> 4;
    const int wr = w >> 1, wc = w & 1;

#pragma unroll
    for (int mi = 0; mi < 4; mi++) {
#pragma unroll
        for (int ni = 0; ni < 4; ni++) {
            const int gn = n0 + wc * 64 + ni * 16 + lrow;
            const float bb = bias[gn];
            const int hh = gn >> 6, dk = gn & 63;
            const int gm0 = m0 + wr * 64 + mi * 16 + lkg * 4;
            const int b2 = gm0 >> 11, ll = gm0 & 2047;
            if (z < 2) {
                unsigned short* C = (z == 0) ? Qh : Kh;
#pragma unroll
                for (int r = 0; r < 4; r++)
                    C[(size_t)((b2 * 16 + hh) * 2048 + ll + r) * 64 + dk] = f2bf(acc[mi][ni][r] + bb);
            } else {
                uint2 o = { pack2(acc[mi][ni][0] + bb, acc[mi][ni][1] + bb),
                            pack2(acc[mi][ni][2] + bb, acc[mi][ni][3] + bb) };
                *(uint2*)&Vt[(size_t)((b2 * 16 + hh) * 64 + dk) * 2048 + ll] = o;
            }
        }
    }
}

// ---------------------------------------------------------------------------
// Output projection: out_f32 = Oh_bf16 @ WoT^T + bo.
// ---------------------------------------------------------------------------
__global__ __launch_bounds__(256) void gemm_o(
    const unsigned short* __restrict__ Oh, const unsigned short* __restrict__ WoT,
    const float* __restrict__ bo, float* __restrict__ out)
{
    const int n0 = blockIdx.x * 128, m0 = blockIdx.y * 128;
    __shared__ unsigned short lA[4096], lB[4096];
    f32x4 acc[4][4];
#pragma unroll
    for (int i = 0; i < 4; i++)
#pragma unroll
        for (int j = 0; j < 4; j++) acc[i][j] = (f32x4){0.f, 0.f, 0.f, 0.f};

    gemm_core(Oh, WoT, lA, lB, m0, n0, acc);

    const int t = threadIdx.x;
    const int w = t >> 6, lane = t & 63, lrow = lane & 15, lkg = lane >> 4;
    const int wr = w >> 1, wc = w & 1;

#pragma unroll
    for (int mi = 0; mi < 4; mi++) {
#pragma unroll
        for (int ni = 0; ni < 4; ni++) {
            const int gn = n0 + wc * 64 + ni * 16 + lrow;
            const float bb = bo[gn];
            const int gm0 = m0 + wr * 64 + mi * 16 + lkg * 4;
#pragma unroll
            for (int r = 0; r < 4; r++)
                out[(size_t)(gm0 + r) * 1024 + gn] = acc[mi][ni][r] + bb;
        }
    }
}

// ---------------------------------------------------------------------------
// Fused attention. 8 waves x 16 q-rows (Q-tile 128).
// Sweep 1: KVBLK=128 K tiles, dbuf, MFMA cluster + exp2 row sums (R4 style).
// Sweep 2: KVBLK=64 K+V tiles, dbuf. NEW: wave-private f32 P stage in LDS
// (stg[w] = [16 q][64 k]); the attn global store is TRANSPOSED through it so
// each nt-store instruction writes 4 rows x 256B CONTIGUOUS segments (vs 16
// rows x 64B before) - 4x DRAM burst length. PV's bf16 P-fragment is derived
// by reading the f32 stage back + pack (identical rounding path as before).
// LDS: 2x16KB KV dbuf + 32KB stage = exactly 64KB static -> 2 blocks/CU.
// ---------------------------------------------------------------------------
__global__ __launch_bounds__(512, 4) void attn_kernel(
    const unsigned short* __restrict__ Qh, const unsigned short* __restrict__ Kh,
    const unsigned short* __restrict__ Vt, float* __restrict__ attn,
    unsigned short* __restrict__ Oh)
{
    const int bid = blockIdx.x;
    const int swz = (bid & 7) * 64 + (bid >> 3);     // XCD-contiguous
    const int bh = swz >> 4;
    const int q0 = (swz & 15) * 128;
    const int b = bh >> 4, h = bh & 15;
    const int t = threadIdx.x;
    const int w = t >> 6, lane = t & 63, ql = lane & 15, kg = lane >> 4;

    __shared__ unsigned short lS[2][8192];   // dbuf: s1: K[128][8 slots]; s2: K[64][8] + V[64][8]
    __shared__ float stg[8][1024];           // per-wave [16 q][64 k] f32 P stage

    const size_t kvbase = (size_t)bh * 2048 * 64;
    const float C = 0.18033688011112042f;    // 0.125 * log2(e)

    const unsigned short* qptr = Qh + kvbase + (size_t)(q0 + w * 16 + ql) * 64 + kg * 8;
    const bf16x8 qf0 = *(const bf16x8*)(qptr);
    const bf16x8 qf1 = *(const bf16x8*)(qptr + 32);

    const unsigned short* Kbh = Kh + kvbase;
    const unsigned short* Vbh = Vt + kvbase;

    // staging coords: wave w covers rows w*8..w*8+7; source col16 pre-swizzled
    const int kr = w * 8 + (lane >> 3);
    const int kc = (lane & 7) ^ (kr & 7);
    const int r7 = ql & 7;

    // ---- sweep 1: denominators (K tiles of 128 rows, double-buffered) ----
    f32x4 ls4 = (f32x4){0.f, 0.f, 0.f, 0.f};
    {
        gl16(Kbh + (size_t)kr * 64 + kc * 8, &lS[0][w * 512]);
        gl16(Kbh + (size_t)(kr + 64) * 64 + kc * 8, &lS[0][4096 + w * 512]);
        __syncthreads();
        for (int kt = 0; kt < 16; ++kt) {
            const int c = kt & 1;
            if (kt < 15) {
                const int k0n = (kt + 1) * 128;
                gl16(Kbh + (size_t)(k0n + kr) * 64 + kc * 8, &lS[c ^ 1][w * 512]);
                gl16(Kbh + (size_t)(k0n + kr + 64) * 64 + kc * 8, &lS[c ^ 1][4096 + w * 512]);
            } else {
                // prefetch sweep-2 tile 0 (K rows 0..63 + V cols 0..63) into lS[0]
                gl16(Kbh + (size_t)kr * 64 + kc * 8, &lS[0][w * 512]);
                gl16(Vbh + (size_t)kr * 2048 + kc * 8, &lS[0][4096 + w * 512]);
            }
            const unsigned short* Kl = lS[c];
            f32x4 sacc[8];
            __builtin_amdgcn_s_setprio(1);
#pragma unroll
            for (int ni = 0; ni < 8; ni++) {
                const int rb = (ni * 16 + ql) * 64;
                bf16x8 kf0 = *(const bf16x8*)&Kl[rb + ((kg ^ r7) * 8)];
                bf16x8 kf1 = *(const bf16x8*)&Kl[rb + (((4 + kg) ^ r7) * 8)];
                f32x4 s = (f32x4){0.f, 0.f, 0.f, 0.f};
                s = MFMA_BF16(kf0, qf0, s, 0, 0, 0);
                sacc[ni] = MFMA_BF16(kf1, qf1, s, 0, 0, 0);
            }
            __builtin_amdgcn_s_setprio(0);
#pragma unroll
            for (int ni = 0; ni < 8; ni++)
#pragma unroll
                for (int r = 0; r < 4; r++) ls4[r] += exp2f(sacc[ni][r] * C);
            __syncthreads();
        }
    }
    float lsum = ls4[0] + ls4[1] + ls4[2] + ls4[3];
    lsum += __shfl_xor(lsum, 16);
    lsum += __shfl_xor(lsum, 32);
    const float mlg = -log2f(lsum);          // p = exp2(S*C - log2 l)

    // ---- sweep 2: attn write + PV (K+V tiles of 64, double-buffered) ----
    f32x4 acco[4];
#pragma unroll
    for (int nv = 0; nv < 4; nv++) acco[nv] = (f32x4){0.f, 0.f, 0.f, 0.f};

    // transposed store base: lane covers col ql*4, rows i*4+kg
    float* abase = attn + ((size_t)bh * 2048 + q0 + w * 16) * 2048 + ql * 4;

    for (int kt = 0; kt < 32; ++kt) {
        const int c = kt & 1;
        if (kt < 31) {
            const int k0n = (kt + 1) * 64;
            gl16(Kbh + (size_t)(k0n + kr) * 64 + kc * 8, &lS[c ^ 1][w * 512]);
            gl16(Vbh + (size_t)kr * 2048 + k0n + kc * 8, &lS[c ^ 1][4096 + w * 512]);
        }
        const int k0 = kt * 64;
        const unsigned short* Kl = lS[c];
        const unsigned short* Vl = &lS[c][4096];

        // QK^T cluster
        f32x4 sacc[4];
        __builtin_amdgcn_s_setprio(1);
#pragma unroll
        for (int ni = 0; ni < 4; ni++) {
            const int rb = (ni * 16 + ql) * 64;
            bf16x8 kf0 = *(const bf16x8*)&Kl[rb + ((kg ^ r7) * 8)];
            bf16x8 kf1 = *(const bf16x8*)&Kl[rb + (((4 + kg) ^ r7) * 8)];
            f32x4 s = (f32x4){0.f, 0.f, 0.f, 0.f};
            s = MFMA_BF16(kf0, qf0, s, 0, 0, 0);
            sacc[ni] = MFMA_BF16(kf1, qf1, s, 0, 0, 0);
        }
        __builtin_amdgcn_s_setprio(0);

        // exp -> f32 stage (wave-private, no barrier needed)
#pragma unroll
        for (int ni = 0; ni < 4; ni++) {
            f32x4 p;
#pragma unroll
            for (int r = 0; r < 4; r++) p[r] = exp2f(fmaf(sacc[ni][r], C, mlg));
            *(f32x4*)&stg[w][ql * 64 + ni * 16 + kg * 4] = p;
        }

        // PV: derive bf16 P-fragment from the f32 stage; O^T += V^T x P^T
        __builtin_amdgcn_s_setprio(1);
#pragma unroll
        for (int s4 = 0; s4 < 2; s4++) {
            const float* ps = &stg[w][ql * 64 + s4 * 32 + kg * 8];
            f32x4 pa = *(const f32x4*)ps;
            f32x4 pb = *(const f32x4*)(ps + 4);
            uint4 pw = { pack2(pa[0], pa[1]), pack2(pa[2], pa[3]),
                         pack2(pb[0], pb[1]), pack2(pb[2], pb[3]) };
            bf16x8 pf = __builtin_bit_cast(bf16x8, pw);
#pragma unroll
            for (int nv = 0; nv < 4; nv++) {
                const int cc = (s4 * 4 + kg) ^ r7;
                bf16x8 vf = *(const bf16x8*)&Vl[(nv * 16 + ql) * 64 + cc * 8];
                acco[nv] = MFMA_BF16(vf, pf, acco[nv], 0, 0, 0);
            }
        }
        __builtin_amdgcn_s_setprio(0);

        // transposed attn store: 4 instrs, each 4 rows x 256B contiguous
#pragma unroll
        for (int i = 0; i < 4; i++) {
            const int row = i * 4 + kg;
            f32x4 vv = *(const f32x4*)&stg[w][row * 64 + ql * 4];
            __builtin_nontemporal_store(vv, (f32x4*)&abase[(size_t)row * 2048 + k0]);
        }
        __syncthreads();
    }

    unsigned short* obase = Oh + ((size_t)(b * 2048 + q0 + w * 16 + ql)) * 1024 + h * 64 + kg * 4;
#pragma unroll
    for (int nv = 0; nv < 4; nv++) {
        uint2 o2 = { pack2(acco[nv][0], acco[nv][1]), pack2(acco[nv][2], acco[nv][3]) };
        *(uint2*)&obase[nv * 16] = o2;
    }
}

// ---------------------------------------------------------------------------
extern "C" void kernel_launch(void* const* d_in, const int* in_sizes, int n_in,
                              void* d_out, int out_size, void* d_ws, size_t ws_size,
                              hipStream_t stream) {
    const float* q  = (const float*)d_in[0];
    const float* k  = (const float*)d_in[1];
    const float* v  = (const float*)d_in[2];
    const float* Wq = (const float*)d_in[3];
    const float* bq = (const float*)d_in[4];
    const float* Wk = (const float*)d_in[5];
    const float* bk = (const float*)d_in[6];
    const float* Wv = (const float*)d_in[7];
    const float* bv = (const float*)d_in[8];
    const float* Wo = (const float*)d_in[9];
    const float* bo = (const float*)d_in[10];

    float* out  = (float*)d_out;                    // [2,2048,1024]
    float* attn = out + (size_t)2 * 2048 * 1024;    // [2,16,2048,2048]

    const size_t HS = 4194304;                      // 2*16*2048*64
    unsigned short* qkvb = (unsigned short*)d_ws;   // 3*HS bf16
    unsigned short* WT   = qkvb + 3 * HS;           // 4 * 1M bf16
    unsigned short* Qh   = WT + 4 * 1048576;        // [B,H,L,64]
    unsigned short* Kh   = Qh + HS;                 // [B,H,L,64]
    unsigned short* Vt   = Kh + HS;                 // [B,H,64,L]
    unsigned short* Oh   = Vt + HS;                 // [B,L,1024]

    conv_wT  <<<dim3(16, 16, 4), 256, 0, stream>>>(Wq, Wk, Wv, Wo, WT);
    conv_bf16<<<dim3(2048, 3),  256, 0, stream>>>(q, k, v, qkvb);
    gemm_qkv <<<dim3(8, 32, 3), 256, 0, stream>>>(qkvb, WT, bq, bk, bv, Qh, Kh, Vt);
    attn_kernel<<<dim3(512), 512, 0, stream>>>(Qh, Kh, Vt, attn, Oh);
    gemm_o   <<<dim3(8, 32),   256, 0, stream>>>(Oh, WT + 3 * 1048576, bo, out);
}

// Round 8
// 248.788 us; speedup vs baseline: 1.2678x; 1.0781x over previous
//
#include <hip/hip_runtime.h>
#include <hip/hip_bf16.h>

typedef float f32x4 __attribute__((ext_vector_type(4)));
typedef short bf16x8 __attribute__((ext_vector_type(8)));

#define MFMA_BF16 __builtin_amdgcn_mfma_f32_16x16x32_bf16

static __device__ __forceinline__ unsigned short f2bf(float f) {
    __hip_bfloat16 h = __float2bfloat16(f);
    return __builtin_bit_cast(unsigned short, h);
}
static __device__ __forceinline__ unsigned int pack2(float a, float b) {
    return (unsigned int)f2bf(a) | ((unsigned int)f2bf(b) << 16);
}

// Async global->LDS, 16B per lane. LDS dest is wave-uniform base + lane*16.
static __device__ __forceinline__ void gl16(const unsigned short* g, unsigned short* l) {
    unsigned short* gg = const_cast<unsigned short*>(g);
    __builtin_amdgcn_global_load_lds(
        (__attribute__((address_space(1))) unsigned int*)gg,
        (__attribute__((address_space(3))) unsigned int*)l, 16, 0, 0);
}

// ---------------------------------------------------------------------------
// Prep 1: W [1024][1024] f32 (k-major) -> Wt [1024][1024] bf16 (n-major, k-contig)
// ---------------------------------------------------------------------------
__global__ __launch_bounds__(256) void conv_wT(
    const float* __restrict__ Wq, const float* __restrict__ Wk,
    const float* __restrict__ Wv, const float* __restrict__ Wo,
    unsigned short* __restrict__ WT)
{
    const int z = blockIdx.z;
    const float* W = (z == 0) ? Wq : (z == 1) ? Wk : (z == 2) ? Wv : Wo;
    unsigned short* Wt = WT + (size_t)z * 1048576;
    const int k0 = blockIdx.x * 64, n0 = blockIdx.y * 64;
    __shared__ float tl[64][68];
    const int t = threadIdx.x;
    const int r = t >> 2, cs = (t & 3) * 16;
#pragma unroll
    for (int j = 0; j < 4; j++)
        *(float4*)&tl[r][cs + j * 4] = *(const float4*)&W[(size_t)(k0 + r) * 1024 + n0 + cs + j * 4];
    __syncthreads();
    const int n = t & 63, kb = (t >> 6) * 16;
#pragma unroll
    for (int j = 0; j < 4; j++) {
        const int kk = kb + j * 4;
        uint2 o = { pack2(tl[kk][n], tl[kk + 1][n]), pack2(tl[kk + 2][n], tl[kk + 3][n]) };
        *(uint2*)&Wt[(size_t)(n0 + n) * 1024 + k0 + kk] = o;
    }
}

// ---------------------------------------------------------------------------
// Prep 2: q/k/v f32 -> bf16. grid (2048, 3).
// ---------------------------------------------------------------------------
__global__ __launch_bounds__(256) void conv_bf16(
    const float* __restrict__ q, const float* __restrict__ k, const float* __restrict__ v,
    unsigned short* __restrict__ qkvb)
{
    const int z = blockIdx.y;
    const float* s = (z == 0) ? q : (z == 1) ? k : v;
    unsigned short* d = qkvb + (size_t)z * 4194304;
    const size_t i = ((size_t)blockIdx.x * 256 + threadIdx.x) * 8;
    float4 a = *(const float4*)&s[i], b = *(const float4*)&s[i + 4];
    uint4 o = { pack2(a.x, a.y), pack2(a.z, a.w), pack2(b.x, b.y), pack2(b.z, b.w) };
    *(uint4*)&d[i] = o;
}

// ---------------------------------------------------------------------------
// Shared GEMM core v2: C(128x128) = A(row-major [M][1024] bf16) x Bt^T.
// Triple-buffered LDS, depth-2 prefetch, counted vmcnt(4) + raw barrier:
// per K-step only the current step's 4 loads are waited; next step's stay
// in flight. vmcnt(0) only on the last step.
// ---------------------------------------------------------------------------
static __device__ __forceinline__ void gemm_core(
    const unsigned short* __restrict__ A, const unsigned short* __restrict__ Bt,
    unsigned short* lA, unsigned short* lB, int m0, int n0, f32x4 (&acc)[4][4])
{
    const int t = threadIdx.x;
    const int w = t >> 6, lane = t & 63, lrow = lane & 15, lkg = lane >> 4;
    const int wr = w >> 1, wc = w & 1;
    const int srow = lane >> 2, sseg = (lane & 3) * 8;

    const unsigned short* Ab0 = &A[(size_t)(m0 + w * 32 + srow) * 1024 + sseg];
    const unsigned short* Ab1 = &A[(size_t)(m0 + w * 32 + 16 + srow) * 1024 + sseg];
    const unsigned short* Bb0 = &Bt[(size_t)(n0 + w * 32 + srow) * 1024 + sseg];
    const unsigned short* Bb1 = &Bt[(size_t)(n0 + w * 32 + 16 + srow) * 1024 + sseg];

#define GISSUE(tt, buf)                                     \
    do {                                                    \
        const int k0_ = (tt) * 32;                          \
        gl16(Ab0 + k0_, &lA[(buf) * 4096 + w * 1024]);      \
        gl16(Ab1 + k0_, &lA[(buf) * 4096 + w * 1024 + 512]);\
        gl16(Bb0 + k0_, &lB[(buf) * 4096 + w * 1024]);      \
        gl16(Bb1 + k0_, &lB[(buf) * 4096 + w * 1024 + 512]);\
    } while (0)

    GISSUE(0, 0);
    GISSUE(1, 1);
    __builtin_amdgcn_sched_barrier(0);

    int bcur = 0;
    for (int tt = 0; tt < 32; ++tt) {
        if (tt < 31) { asm volatile("s_waitcnt vmcnt(4)" ::: "memory"); }
        else         { asm volatile("s_waitcnt vmcnt(0)" ::: "memory"); }
        __builtin_amdgcn_s_barrier();
        __builtin_amdgcn_sched_barrier(0);
        if (tt + 2 < 32) {
            int bpre = bcur + 2; if (bpre >= 3) bpre -= 3;
            GISSUE(tt + 2, bpre);
        }
        __builtin_amdgcn_sched_barrier(0);

        const unsigned short* la = &lA[bcur * 4096];
        const unsigned short* lb = &lB[bcur * 4096];
        bf16x8 af[4], bfr[4];
#pragma unroll
        for (int mi = 0; mi < 4; mi++)
            af[mi] = *(const bf16x8*)&la[(wr * 64 + mi * 16 + lrow) * 32 + lkg * 8];
#pragma unroll
        for (int ni = 0; ni < 4; ni++)
            bfr[ni] = *(const bf16x8*)&lb[(wc * 64 + ni * 16 + lrow) * 32 + lkg * 8];
        __builtin_amdgcn_s_setprio(1);
#pragma unroll
        for (int mi = 0; mi < 4; mi++)
#pragma unroll
            for (int ni = 0; ni < 4; ni++)
                acc[mi][ni] = MFMA_BF16(af[mi], bfr[ni], acc[mi][ni], 0, 0, 0);
        __builtin_amdgcn_s_setprio(0);
        bcur = (bcur == 2) ? 0 : bcur + 1;
    }
#undef GISSUE
}

// ---------------------------------------------------------------------------
// QKV projections, 1D XCD-chunked grid (768 = 8 XCD x 96).
// z=0: Q->[B,H,L,64]; z=1: K->[B,H,L,64]; z=2: V->[B,H,64,L].
// ---------------------------------------------------------------------------
__global__ __launch_bounds__(256) void gemm_qkv(
    const unsigned short* __restrict__ qkvb, const unsigned short* __restrict__ WT,
    const float* __restrict__ bq, const float* __restrict__ bk, const float* __restrict__ bv,
    unsigned short* __restrict__ Qh, unsigned short* __restrict__ Kh, unsigned short* __restrict__ Vt)
{
    const int u0 = blockIdx.x;
    const int u = (u0 & 7) * 96 + (u0 >> 3);       // XCD-contiguous chunks
    const int z = u >> 8, rm = u & 255;
    const int m0 = ((rm >> 3) & 31) * 128, n0 = (rm & 7) * 128;

    const unsigned short* A = qkvb + (size_t)z * 4194304;
    const unsigned short* Bt = WT + (size_t)z * 1048576;
    const float* bias = (z == 0) ? bq : (z == 1) ? bk : bv;

    __shared__ unsigned short lA[3 * 4096], lB[3 * 4096];
    f32x4 acc[4][4];
#pragma unroll
    for (int i = 0; i < 4; i++)
#pragma unroll
        for (int j = 0; j < 4; j++) acc[i][j] = (f32x4){0.f, 0.f, 0.f, 0.f};

    gemm_core(A, Bt, lA, lB, m0, n0, acc);

    const int t = threadIdx.x;
    const int w = t >> 6, lane = t & 63, lrow = lane & 15, lkg = lane >> 4;
    const int wr = w >> 1, wc = w & 1;

#pragma unroll
    for (int mi = 0; mi < 4; mi++) {
#pragma unroll
        for (int ni = 0; ni < 4; ni++) {
            const int gn = n0 + wc * 64 + ni * 16 + lrow;
            const float bb = bias[gn];
            const int hh = gn >> 6, dk = gn & 63;
            const int gm0 = m0 + wr * 64 + mi * 16 + lkg * 4;
            const int b2 = gm0 >> 11, ll = gm0 & 2047;
            if (z < 2) {
                unsigned short* C = (z == 0) ? Qh : Kh;
#pragma unroll
                for (int r = 0; r < 4; r++)
                    C[(size_t)((b2 * 16 + hh) * 2048 + ll + r) * 64 + dk] = f2bf(acc[mi][ni][r] + bb);
            } else {
                uint2 o = { pack2(acc[mi][ni][0] + bb, acc[mi][ni][1] + bb),
                            pack2(acc[mi][ni][2] + bb, acc[mi][ni][3] + bb) };
                *(uint2*)&Vt[(size_t)((b2 * 16 + hh) * 64 + dk) * 2048 + ll] = o;
            }
        }
    }
}

// ---------------------------------------------------------------------------
// Output projection, 1D XCD-chunked grid (256 = 8 x 32).
// ---------------------------------------------------------------------------
__global__ __launch_bounds__(256) void gemm_o(
    const unsigned short* __restrict__ Oh, const unsigned short* __restrict__ WoT,
    const float* __restrict__ bo, float* __restrict__ out)
{
    const int u0 = blockIdx.x;
    const int u = (u0 & 7) * 32 + (u0 >> 3);
    const int m0 = (u >> 3) * 128, n0 = (u & 7) * 128;

    __shared__ unsigned short lA[3 * 4096], lB[3 * 4096];
    f32x4 acc[4][4];
#pragma unroll
    for (int i = 0; i < 4; i++)
#pragma unroll
        for (int j = 0; j < 4; j++) acc[i][j] = (f32x4){0.f, 0.f, 0.f, 0.f};

    gemm_core(Oh, WoT, lA, lB, m0, n0, acc);

    const int t = threadIdx.x;
    const int w = t >> 6, lane = t & 63, lrow = lane & 15, lkg = lane >> 4;
    const int wr = w >> 1, wc = w & 1;

#pragma unroll
    for (int mi = 0; mi < 4; mi++) {
#pragma unroll
        for (int ni = 0; ni < 4; ni++) {
            const int gn = n0 + wc * 64 + ni * 16 + lrow;
            const float bb = bo[gn];
            const int gm0 = m0 + wr * 64 + mi * 16 + lkg * 4;
#pragma unroll
            for (int r = 0; r < 4; r++)
                out[(size_t)(gm0 + r) * 1024 + gn] = acc[mi][ni][r] + bb;
        }
    }
}

// ---------------------------------------------------------------------------
// Fused attention (R7 structure, unchanged). 8 waves x 16 q-rows.
// Sweep 1: KVBLK=128 K tiles, dbuf, MFMA cluster + exp2 row sums.
// Sweep 2: KVBLK=64 K+V tiles, dbuf, wave-private f32 P stage; transposed
// nt-stores (4 rows x 256B contiguous per instr). PV derives bf16 P from
// the f32 stage. LDS: 2x16KB KV dbuf + 32KB stage = 64KB.
// ---------------------------------------------------------------------------
__global__ __launch_bounds__(512, 4) void attn_kernel(
    const unsigned short* __restrict__ Qh, const unsigned short* __restrict__ Kh,
    const unsigned short* __restrict__ Vt, float* __restrict__ attn,
    unsigned short* __restrict__ Oh)
{
    const int bid = blockIdx.x;
    const int swz = (bid & 7) * 64 + (bid >> 3);     // XCD-contiguous
    const int bh = swz >> 4;
    const int q0 = (swz & 15) * 128;
    const int b = bh >> 4, h = bh & 15;
    const int t = threadIdx.x;
    const int w = t >> 6, lane = t & 63, ql = lane & 15, kg = lane >> 4;

    __shared__ unsigned short lS[2][8192];   // dbuf: s1: K[128][8 slots]; s2: K[64][8] + V[64][8]
    __shared__ float stg[8][1024];           // per-wave [16 q][64 k] f32 P stage

    const size_t kvbase = (size_t)bh * 2048 * 64;
    const float C = 0.18033688011112042f;    // 0.125 * log2(e)

    const unsigned short* qptr = Qh + kvbase + (size_t)(q0 + w * 16 + ql) * 64 + kg * 8;
    const bf16x8 qf0 = *(const bf16x8*)(qptr);
    const bf16x8 qf1 = *(const bf16x8*)(qptr + 32);

    const unsigned short* Kbh = Kh + kvbase;
    const unsigned short* Vbh = Vt + kvbase;

    const int kr = w * 8 + (lane >> 3);
    const int kc = (lane & 7) ^ (kr & 7);
    const int r7 = ql & 7;

    // ---- sweep 1: denominators (K tiles of 128 rows, double-buffered) ----
    f32x4 ls4 = (f32x4){0.f, 0.f, 0.f, 0.f};
    {
        gl16(Kbh + (size_t)kr * 64 + kc * 8, &lS[0][w * 512]);
        gl16(Kbh + (size_t)(kr + 64) * 64 + kc * 8, &lS[0][4096 + w * 512]);
        __syncthreads();
        for (int kt = 0; kt < 16; ++kt) {
            const int c = kt & 1;
            if (kt < 15) {
                const int k0n = (kt + 1) * 128;
                gl16(Kbh + (size_t)(k0n + kr) * 64 + kc * 8, &lS[c ^ 1][w * 512]);
                gl16(Kbh + (size_t)(k0n + kr + 64) * 64 + kc * 8, &lS[c ^ 1][4096 + w * 512]);
            } else {
                gl16(Kbh + (size_t)kr * 64 + kc * 8, &lS[0][w * 512]);
                gl16(Vbh + (size_t)kr * 2048 + kc * 8, &lS[0][4096 + w * 512]);
            }
            const unsigned short* Kl = lS[c];
            f32x4 sacc[8];
            __builtin_amdgcn_s_setprio(1);
#pragma unroll
            for (int ni = 0; ni < 8; ni++) {
                const int rb = (ni * 16 + ql) * 64;
                bf16x8 kf0 = *(const bf16x8*)&Kl[rb + ((kg ^ r7) * 8)];
                bf16x8 kf1 = *(const bf16x8*)&Kl[rb + (((4 + kg) ^ r7) * 8)];
                f32x4 s = (f32x4){0.f, 0.f, 0.f, 0.f};
                s = MFMA_BF16(kf0, qf0, s, 0, 0, 0);
                sacc[ni] = MFMA_BF16(kf1, qf1, s, 0, 0, 0);
            }
            __builtin_amdgcn_s_setprio(0);
#pragma unroll
            for (int ni = 0; ni < 8; ni++)
#pragma unroll
                for (int r = 0; r < 4; r++) ls4[r] += exp2f(sacc[ni][r] * C);
            __syncthreads();
        }
    }
    float lsum = ls4[0] + ls4[1] + ls4[2] + ls4[3];
    lsum += __shfl_xor(lsum, 16);
    lsum += __shfl_xor(lsum, 32);
    const float mlg = -log2f(lsum);          // p = exp2(S*C - log2 l)

    // ---- sweep 2: attn write + PV (K+V tiles of 64, double-buffered) ----
    f32x4 acco[4];
#pragma unroll
    for (int nv = 0; nv < 4; nv++) acco[nv] = (f32x4){0.f, 0.f, 0.f, 0.f};

    float* abase = attn + ((size_t)bh * 2048 + q0 + w * 16) * 2048 + ql * 4;

    for (int kt = 0; kt < 32; ++kt) {
        const int c = kt & 1;
        if (kt < 31) {
            const int k0n = (kt + 1) * 64;
            gl16(Kbh + (size_t)(k0n + kr) * 64 + kc * 8, &lS[c ^ 1][w * 512]);
            gl16(Vbh + (size_t)kr * 2048 + k0n + kc * 8, &lS[c ^ 1][4096 + w * 512]);
        }
        const int k0 = kt * 64;
        const unsigned short* Kl = lS[c];
        const unsigned short* Vl = &lS[c][4096];

        f32x4 sacc[4];
        __builtin_amdgcn_s_setprio(1);
#pragma unroll
        for (int ni = 0; ni < 4; ni++) {
            const int rb = (ni * 16 + ql) * 64;
            bf16x8 kf0 = *(const bf16x8*)&Kl[rb + ((kg ^ r7) * 8)];
            bf16x8 kf1 = *(const bf16x8*)&Kl[rb + (((4 + kg) ^ r7) * 8)];
            f32x4 s = (f32x4){0.f, 0.f, 0.f, 0.f};
            s = MFMA_BF16(kf0, qf0, s, 0, 0, 0);
            sacc[ni] = MFMA_BF16(kf1, qf1, s, 0, 0, 0);
        }
        __builtin_amdgcn_s_setprio(0);

#pragma unroll
        for (int ni = 0; ni < 4; ni++) {
            f32x4 p;
#pragma unroll
            for (int r = 0; r < 4; r++) p[r] = exp2f(fmaf(sacc[ni][r], C, mlg));
            *(f32x4*)&stg[w][ql * 64 + ni * 16 + kg * 4] = p;
        }

        __builtin_amdgcn_s_setprio(1);
#pragma unroll
        for (int s4 = 0; s4 < 2; s4++) {
            const float* ps = &stg[w][ql * 64 + s4 * 32 + kg * 8];
            f32x4 pa = *(const f32x4*)ps;
            f32x4 pb = *(const f32x4*)(ps + 4);
            uint4 pw = { pack2(pa[0], pa[1]), pack2(pa[2], pa[3]),
                         pack2(pb[0], pb[1]), pack2(pb[2], pb[3]) };
            bf16x8 pf = __builtin_bit_cast(bf16x8, pw);
#pragma unroll
            for (int nv = 0; nv < 4; nv++) {
                const int cc = (s4 * 4 + kg) ^ r7;
                bf16x8 vf = *(const bf16x8*)&Vl[(nv * 16 + ql) * 64 + cc * 8];
                acco[nv] = MFMA_BF16(vf, pf, acco[nv], 0, 0, 0);
            }
        }
        __builtin_amdgcn_s_setprio(0);

#pragma unroll
        for (int i = 0; i < 4; i++) {
            const int row = i * 4 + kg;
            f32x4 vv = *(const f32x4*)&stg[w][row * 64 + ql * 4];
            __builtin_nontemporal_store(vv, (f32x4*)&abase[(size_t)row * 2048 + k0]);
        }
        __syncthreads();
    }

    unsigned short* obase = Oh + ((size_t)(b * 2048 + q0 + w * 16 + ql)) * 1024 + h * 64 + kg * 4;
#pragma unroll
    for (int nv = 0; nv < 4; nv++) {
        uint2 o2 = { pack2(acco[nv][0], acco[nv][1]), pack2(acco[nv][2], acco[nv][3]) };
        *(uint2*)&obase[nv * 16] = o2;
    }
}

// ---------------------------------------------------------------------------
extern "C" void kernel_launch(void* const* d_in, const int* in_sizes, int n_in,
                              void* d_out, int out_size, void* d_ws, size_t ws_size,
                              hipStream_t stream) {
    const float* q  = (const float*)d_in[0];
    const float* k  = (const float*)d_in[1];
    const float* v  = (const float*)d_in[2];
    const float* Wq = (const float*)d_in[3];
    const float* bq = (const float*)d_in[4];
    const float* Wk = (const float*)d_in[5];
    const float* bk = (const float*)d_in[6];
    const float* Wv = (const float*)d_in[7];
    const float* bv = (const float*)d_in[8];
    const float* Wo = (const float*)d_in[9];
    const float* bo = (const float*)d_in[10];

    float* out  = (float*)d_out;                    // [2,2048,1024]
    float* attn = out + (size_t)2 * 2048 * 1024;    // [2,16,2048,2048]

    const size_t HS = 4194304;                      // 2*16*2048*64
    unsigned short* qkvb = (unsigned short*)d_ws;   // 3*HS bf16
    unsigned short* WT   = qkvb + 3 * HS;           // 4 * 1M bf16
    unsigned short* Qh   = WT + 4 * 1048576;        // [B,H,L,64]
    unsigned short* Kh   = Qh + HS;                 // [B,H,L,64]
    unsigned short* Vt   = Kh + HS;                 // [B,H,64,L]
    unsigned short* Oh   = Vt + HS;                 // [B,L,1024]

    conv_wT  <<<dim3(16, 16, 4), 256, 0, stream>>>(Wq, Wk, Wv, Wo, WT);
    conv_bf16<<<dim3(2048, 3),  256, 0, stream>>>(q, k, v, qkvb);
    gemm_qkv <<<dim3(768), 256, 0, stream>>>(qkvb, WT, bq, bk, bv, Qh, Kh, Vt);
    attn_kernel<<<dim3(512), 512, 0, stream>>>(Qh, Kh, Vt, attn, Oh);
    gemm_o   <<<dim3(256), 256, 0, stream>>>(Oh, WT + 3 * 1048576, bo, out);
}

// Round 9
// 242.333 us; speedup vs baseline: 1.3015x; 1.0266x over previous
//
#include <hip/hip_runtime.h>
#include <hip/hip_bf16.h>

typedef float f32x4 __attribute__((ext_vector_type(4)));
typedef short bf16x8 __attribute__((ext_vector_type(8)));

#define MFMA_BF16 __builtin_amdgcn_mfma_f32_16x16x32_bf16

static __device__ __forceinline__ unsigned short f2bf(float f) {
    __hip_bfloat16 h = __float2bfloat16(f);
    return __builtin_bit_cast(unsigned short, h);
}
static __device__ __forceinline__ unsigned int pack2(float a, float b) {
    return (unsigned int)f2bf(a) | ((unsigned int)f2bf(b) << 16);
}

// Async global->LDS, 16B per lane. LDS dest is wave-uniform base + lane*16.
static __device__ __forceinline__ void gl16(const unsigned short* g, unsigned short* l) {
    unsigned short* gg = const_cast<unsigned short*>(g);
    __builtin_amdgcn_global_load_lds(
        (__attribute__((address_space(1))) unsigned int*)gg,
        (__attribute__((address_space(3))) unsigned int*)l, 16, 0, 0);
}

// ---------------------------------------------------------------------------
// Prep 1: W [1024][1024] f32 (k-major) -> Wt [1024][1024] bf16 (n-major, k-contig)
// ---------------------------------------------------------------------------
__global__ __launch_bounds__(256) void conv_wT(
    const float* __restrict__ Wq, const float* __restrict__ Wk,
    const float* __restrict__ Wv, const float* __restrict__ Wo,
    unsigned short* __restrict__ WT)
{
    const int z = blockIdx.z;
    const float* W = (z == 0) ? Wq : (z == 1) ? Wk : (z == 2) ? Wv : Wo;
    unsigned short* Wt = WT + (size_t)z * 1048576;
    const int k0 = blockIdx.x * 64, n0 = blockIdx.y * 64;
    __shared__ float tl[64][68];
    const int t = threadIdx.x;
    const int r = t >> 2, cs = (t & 3) * 16;
#pragma unroll
    for (int j = 0; j < 4; j++)
        *(float4*)&tl[r][cs + j * 4] = *(const float4*)&W[(size_t)(k0 + r) * 1024 + n0 + cs + j * 4];
    __syncthreads();
    const int n = t & 63, kb = (t >> 6) * 16;
#pragma unroll
    for (int j = 0; j < 4; j++) {
        const int kk = kb + j * 4;
        uint2 o = { pack2(tl[kk][n], tl[kk + 1][n]), pack2(tl[kk + 2][n], tl[kk + 3][n]) };
        *(uint2*)&Wt[(size_t)(n0 + n) * 1024 + k0 + kk] = o;
    }
}

// ---------------------------------------------------------------------------
// Prep 2: q/k/v f32 -> bf16. grid (2048, 3).
// ---------------------------------------------------------------------------
__global__ __launch_bounds__(256) void conv_bf16(
    const float* __restrict__ q, const float* __restrict__ k, const float* __restrict__ v,
    unsigned short* __restrict__ qkvb)
{
    const int z = blockIdx.y;
    const float* s = (z == 0) ? q : (z == 1) ? k : v;
    unsigned short* d = qkvb + (size_t)z * 4194304;
    const size_t i = ((size_t)blockIdx.x * 256 + threadIdx.x) * 8;
    float4 a = *(const float4*)&s[i], b = *(const float4*)&s[i + 4];
    uint4 o = { pack2(a.x, a.y), pack2(a.z, a.w), pack2(b.x, b.y), pack2(b.z, b.w) };
    *(uint4*)&d[i] = o;
}

// ---------------------------------------------------------------------------
// Shared GEMM core v2: C(128x128) = A(row-major [M][1024] bf16) x Bt^T.
// Triple-buffered LDS, depth-2 prefetch, counted vmcnt(4) + raw barrier.
// NO memory clobber on the waitcnt asm (m201 pattern) — a clobber can force
// the compiler to pre-drain, nullifying the counted wait.
// ---------------------------------------------------------------------------
static __device__ __forceinline__ void gemm_core(
    const unsigned short* __restrict__ A, const unsigned short* __restrict__ Bt,
    unsigned short* lA, unsigned short* lB, int m0, int n0, f32x4 (&acc)[4][4])
{
    const int t = threadIdx.x;
    const int w = t >> 6, lane = t & 63, lrow = lane & 15, lkg = lane >> 4;
    const int wr = w >> 1, wc = w & 1;
    const int srow = lane >> 2, sseg = (lane & 3) * 8;

    const unsigned short* Ab0 = &A[(size_t)(m0 + w * 32 + srow) * 1024 + sseg];
    const unsigned short* Ab1 = &A[(size_t)(m0 + w * 32 + 16 + srow) * 1024 + sseg];
    const unsigned short* Bb0 = &Bt[(size_t)(n0 + w * 32 + srow) * 1024 + sseg];
    const unsigned short* Bb1 = &Bt[(size_t)(n0 + w * 32 + 16 + srow) * 1024 + sseg];

#define GISSUE(tt, buf)                                     \
    do {                                                    \
        const int k0_ = (tt) * 32;                          \
        gl16(Ab0 + k0_, &lA[(buf) * 4096 + w * 1024]);      \
        gl16(Ab1 + k0_, &lA[(buf) * 4096 + w * 1024 + 512]);\
        gl16(Bb0 + k0_, &lB[(buf) * 4096 + w * 1024]);      \
        gl16(Bb1 + k0_, &lB[(buf) * 4096 + w * 1024 + 512]);\
    } while (0)

    GISSUE(0, 0);
    GISSUE(1, 1);
    __builtin_amdgcn_sched_barrier(0);

    int bcur = 0;
    for (int tt = 0; tt < 32; ++tt) {
        if (tt < 31) { asm volatile("s_waitcnt vmcnt(4)"); }
        else         { asm volatile("s_waitcnt vmcnt(0)"); }
        __builtin_amdgcn_s_barrier();
        __builtin_amdgcn_sched_barrier(0);
        if (tt + 2 < 32) {
            int bpre = bcur + 2; if (bpre >= 3) bpre -= 3;
            GISSUE(tt + 2, bpre);
        }
        __builtin_amdgcn_sched_barrier(0);

        const unsigned short* la = &lA[bcur * 4096];
        const unsigned short* lb = &lB[bcur * 4096];
        bf16x8 af[4], bfr[4];
#pragma unroll
        for (int mi = 0; mi < 4; mi++)
            af[mi] = *(const bf16x8*)&la[(wr * 64 + mi * 16 + lrow) * 32 + lkg * 8];
#pragma unroll
        for (int ni = 0; ni < 4; ni++)
            bfr[ni] = *(const bf16x8*)&lb[(wc * 64 + ni * 16 + lrow) * 32 + lkg * 8];
        __builtin_amdgcn_s_setprio(1);
#pragma unroll
        for (int mi = 0; mi < 4; mi++)
#pragma unroll
            for (int ni = 0; ni < 4; ni++)
                acc[mi][ni] = MFMA_BF16(af[mi], bfr[ni], acc[mi][ni], 0, 0, 0);
        __builtin_amdgcn_s_setprio(0);
        bcur = (bcur == 2) ? 0 : bcur + 1;
    }
#undef GISSUE
}

// ---------------------------------------------------------------------------
// QKV projections, 1D XCD-chunked grid (768 = 8 XCD x 96).
// z=0: Q->[B,H,L,64]; z=1: K->[B,H,L,64]; z=2: V->[B,H,64,L].
// ---------------------------------------------------------------------------
__global__ __launch_bounds__(256) void gemm_qkv(
    const unsigned short* __restrict__ qkvb, const unsigned short* __restrict__ WT,
    const float* __restrict__ bq, const float* __restrict__ bk, const float* __restrict__ bv,
    unsigned short* __restrict__ Qh, unsigned short* __restrict__ Kh, unsigned short* __restrict__ Vt)
{
    const int u0 = blockIdx.x;
    const int u = (u0 & 7) * 96 + (u0 >> 3);       // XCD-contiguous chunks
    const int z = u >> 8, rm = u & 255;
    const int m0 = ((rm >> 3) & 31) * 128, n0 = (rm & 7) * 128;

    const unsigned short* A = qkvb + (size_t)z * 4194304;
    const unsigned short* Bt = WT + (size_t)z * 1048576;
    const float* bias = (z == 0) ? bq : (z == 1) ? bk : bv;

    __shared__ unsigned short lA[3 * 4096], lB[3 * 4096];
    f32x4 acc[4][4];
#pragma unroll
    for (int i = 0; i < 4; i++)
#pragma unroll
        for (int j = 0; j < 4; j++) acc[i][j] = (f32x4){0.f, 0.f, 0.f, 0.f};

    gemm_core(A, Bt, lA, lB, m0, n0, acc);

    const int t = threadIdx.x;
    const int w = t >> 6, lane = t & 63, lrow = lane & 15, lkg = lane >> 4;
    const int wr = w >> 1, wc = w & 1;

#pragma unroll
    for (int mi = 0; mi < 4; mi++) {
#pragma unroll
        for (int ni = 0; ni < 4; ni++) {
            const int gn = n0 + wc * 64 + ni * 16 + lrow;
            const float bb = bias[gn];
            const int hh = gn >> 6, dk = gn & 63;
            const int gm0 = m0 + wr * 64 + mi * 16 + lkg * 4;
            const int b2 = gm0 >> 11, ll = gm0 & 2047;
            if (z < 2) {
                unsigned short* C = (z == 0) ? Qh : Kh;
#pragma unroll
                for (int r = 0; r < 4; r++)
                    C[(size_t)((b2 * 16 + hh) * 2048 + ll + r) * 64 + dk] = f2bf(acc[mi][ni][r] + bb);
            } else {
                uint2 o = { pack2(acc[mi][ni][0] + bb, acc[mi][ni][1] + bb),
                            pack2(acc[mi][ni][2] + bb, acc[mi][ni][3] + bb) };
                *(uint2*)&Vt[(size_t)((b2 * 16 + hh) * 64 + dk) * 2048 + ll] = o;
            }
        }
    }
}

// ---------------------------------------------------------------------------
// Output projection, 1D XCD-chunked grid (256 = 8 x 32).
// ---------------------------------------------------------------------------
__global__ __launch_bounds__(256) void gemm_o(
    const unsigned short* __restrict__ Oh, const unsigned short* __restrict__ WoT,
    const float* __restrict__ bo, float* __restrict__ out)
{
    const int u0 = blockIdx.x;
    const int u = (u0 & 7) * 32 + (u0 >> 3);
    const int m0 = (u >> 3) * 128, n0 = (u & 7) * 128;

    __shared__ unsigned short lA[3 * 4096], lB[3 * 4096];
    f32x4 acc[4][4];
#pragma unroll
    for (int i = 0; i < 4; i++)
#pragma unroll
        for (int j = 0; j < 4; j++) acc[i][j] = (f32x4){0.f, 0.f, 0.f, 0.f};

    gemm_core(Oh, WoT, lA, lB, m0, n0, acc);

    const int t = threadIdx.x;
    const int w = t >> 6, lane = t & 63, lrow = lane & 15, lkg = lane >> 4;
    const int wr = w >> 1, wc = w & 1;

#pragma unroll
    for (int mi = 0; mi < 4; mi++) {
#pragma unroll
        for (int ni = 0; ni < 4; ni++) {
            const int gn = n0 + wc * 64 + ni * 16 + lrow;
            const float bb = bo[gn];
            const int gm0 = m0 + wr * 64 + mi * 16 + lkg * 4;
#pragma unroll
            for (int r = 0; r < 4; r++)
                out[(size_t)(gm0 + r) * 1024 + gn] = acc[mi][ni][r] + bb;
        }
    }
}

// ---------------------------------------------------------------------------
// Fused attention. 8 waves x 16 q-rows (Q-tile 128).
// Sweep 1: KVBLK=128 K tiles, dbuf, __syncthreads (no stores -> cheap drain).
// Sweep 2: KVBLK=64 K+V tiles, dbuf. Order per tile: prefetch -> QK -> exp ->
// stg -> TRANSPOSED nt stores (issued EARLY) -> PV (overlaps store drain) ->
// s_waitcnt vmcnt(4) [no clobber] + raw s_barrier: retires prev-tile stores +
// this tile's 2 prefetch loads, leaves this tile's 4 stores draining under
// the next tile's compute. LDS: 2x16KB KV dbuf + 32KB stage = 64KB.
// ---------------------------------------------------------------------------
__global__ __launch_bounds__(512, 4) void attn_kernel(
    const unsigned short* __restrict__ Qh, const unsigned short* __restrict__ Kh,
    const unsigned short* __restrict__ Vt, float* __restrict__ attn,
    unsigned short* __restrict__ Oh)
{
    const int bid = blockIdx.x;
    const int swz = (bid & 7) * 64 + (bid >> 3);     // XCD-contiguous
    const int bh = swz >> 4;
    const int q0 = (swz & 15) * 128;
    const int b = bh >> 4, h = bh & 15;
    const int t = threadIdx.x;
    const int w = t >> 6, lane = t & 63, ql = lane & 15, kg = lane >> 4;

    __shared__ unsigned short lS[2][8192];   // dbuf: s1: K[128][8 slots]; s2: K[64][8] + V[64][8]
    __shared__ float stg[8][1024];           // per-wave [16 q][64 k] f32 P stage

    const size_t kvbase = (size_t)bh * 2048 * 64;
    const float C = 0.18033688011112042f;    // 0.125 * log2(e)

    const unsigned short* qptr = Qh + kvbase + (size_t)(q0 + w * 16 + ql) * 64 + kg * 8;
    const bf16x8 qf0 = *(const bf16x8*)(qptr);
    const bf16x8 qf1 = *(const bf16x8*)(qptr + 32);

    const unsigned short* Kbh = Kh + kvbase;
    const unsigned short* Vbh = Vt + kvbase;

    const int kr = w * 8 + (lane >> 3);
    const int kc = (lane & 7) ^ (kr & 7);
    const int r7 = ql & 7;

    // ---- sweep 1: denominators (K tiles of 128 rows, double-buffered) ----
    f32x4 ls4 = (f32x4){0.f, 0.f, 0.f, 0.f};
    {
        gl16(Kbh + (size_t)kr * 64 + kc * 8, &lS[0][w * 512]);
        gl16(Kbh + (size_t)(kr + 64) * 64 + kc * 8, &lS[0][4096 + w * 512]);
        __syncthreads();
        for (int kt = 0; kt < 16; ++kt) {
            const int c = kt & 1;
            if (kt < 15) {
                const int k0n = (kt + 1) * 128;
                gl16(Kbh + (size_t)(k0n + kr) * 64 + kc * 8, &lS[c ^ 1][w * 512]);
                gl16(Kbh + (size_t)(k0n + kr + 64) * 64 + kc * 8, &lS[c ^ 1][4096 + w * 512]);
            } else {
                gl16(Kbh + (size_t)kr * 64 + kc * 8, &lS[0][w * 512]);
                gl16(Vbh + (size_t)kr * 2048 + kc * 8, &lS[0][4096 + w * 512]);
            }
            const unsigned short* Kl = lS[c];
            f32x4 sacc[8];
            __builtin_amdgcn_s_setprio(1);
#pragma unroll
            for (int ni = 0; ni < 8; ni++) {
                const int rb = (ni * 16 + ql) * 64;
                bf16x8 kf0 = *(const bf16x8*)&Kl[rb + ((kg ^ r7) * 8)];
                bf16x8 kf1 = *(const bf16x8*)&Kl[rb + (((4 + kg) ^ r7) * 8)];
                f32x4 s = (f32x4){0.f, 0.f, 0.f, 0.f};
                s = MFMA_BF16(kf0, qf0, s, 0, 0, 0);
                sacc[ni] = MFMA_BF16(kf1, qf1, s, 0, 0, 0);
            }
            __builtin_amdgcn_s_setprio(0);
#pragma unroll
            for (int ni = 0; ni < 8; ni++)
#pragma unroll
                for (int r = 0; r < 4; r++) ls4[r] += exp2f(sacc[ni][r] * C);
            __syncthreads();
        }
    }
    float lsum = ls4[0] + ls4[1] + ls4[2] + ls4[3];
    lsum += __shfl_xor(lsum, 16);
    lsum += __shfl_xor(lsum, 32);
    const float mlg = -log2f(lsum);          // p = exp2(S*C - log2 l)

    // ---- sweep 2: attn write + PV (K+V tiles of 64, double-buffered) ----
    f32x4 acco[4];
#pragma unroll
    for (int nv = 0; nv < 4; nv++) acco[nv] = (f32x4){0.f, 0.f, 0.f, 0.f};

    float* abase = attn + ((size_t)bh * 2048 + q0 + w * 16) * 2048 + ql * 4;

    for (int kt = 0; kt < 32; ++kt) {
        const int c = kt & 1;
        if (kt < 31) {
            const int k0n = (kt + 1) * 64;
            gl16(Kbh + (size_t)(k0n + kr) * 64 + kc * 8, &lS[c ^ 1][w * 512]);
            gl16(Vbh + (size_t)kr * 2048 + k0n + kc * 8, &lS[c ^ 1][4096 + w * 512]);
        }
        __builtin_amdgcn_sched_barrier(0);
        const int k0 = kt * 64;
        const unsigned short* Kl = lS[c];
        const unsigned short* Vl = &lS[c][4096];

        // QK^T cluster
        f32x4 sacc[4];
        __builtin_amdgcn_s_setprio(1);
#pragma unroll
        for (int ni = 0; ni < 4; ni++) {
            const int rb = (ni * 16 + ql) * 64;
            bf16x8 kf0 = *(const bf16x8*)&Kl[rb + ((kg ^ r7) * 8)];
            bf16x8 kf1 = *(const bf16x8*)&Kl[rb + (((4 + kg) ^ r7) * 8)];
            f32x4 s = (f32x4){0.f, 0.f, 0.f, 0.f};
            s = MFMA_BF16(kf0, qf0, s, 0, 0, 0);
            sacc[ni] = MFMA_BF16(kf1, qf1, s, 0, 0, 0);
        }
        __builtin_amdgcn_s_setprio(0);

        // exp -> f32 stage (wave-private)
#pragma unroll
        for (int ni = 0; ni < 4; ni++) {
            f32x4 p;
#pragma unroll
            for (int r = 0; r < 4; r++) p[r] = exp2f(fmaf(sacc[ni][r], C, mlg));
            *(f32x4*)&stg[w][ql * 64 + ni * 16 + kg * 4] = p;
        }

        // transposed attn stores ISSUED EARLY (drain overlaps PV below)
#pragma unroll
        for (int i = 0; i < 4; i++) {
            const int row = i * 4 + kg;
            f32x4 vv = *(const f32x4*)&stg[w][row * 64 + ql * 4];
            __builtin_nontemporal_store(vv, (f32x4*)&abase[(size_t)row * 2048 + k0]);
        }

        // PV: derive bf16 P from the f32 stage; O^T += V^T x P^T
        __builtin_amdgcn_s_setprio(1);
#pragma unroll
        for (int s4 = 0; s4 < 2; s4++) {
            const float* ps = &stg[w][ql * 64 + s4 * 32 + kg * 8];
            f32x4 pa = *(const f32x4*)ps;
            f32x4 pb = *(const f32x4*)(ps + 4);
            uint4 pw = { pack2(pa[0], pa[1]), pack2(pa[2], pa[3]),
                         pack2(pb[0], pb[1]), pack2(pb[2], pb[3]) };
            bf16x8 pf = __builtin_bit_cast(bf16x8, pw);
#pragma unroll
            for (int nv = 0; nv < 4; nv++) {
                const int cc = (s4 * 4 + kg) ^ r7;
                bf16x8 vf = *(const bf16x8*)&Vl[(nv * 16 + ql) * 64 + cc * 8];
                acco[nv] = MFMA_BF16(vf, pf, acco[nv], 0, 0, 0);
            }
        }
        __builtin_amdgcn_s_setprio(0);

        // counted barrier: retire prev-tile stores + this tile's prefetch
        // loads; leave this tile's 4 stores in flight.
        asm volatile("s_waitcnt vmcnt(4)");
        __builtin_amdgcn_s_barrier();
        __builtin_amdgcn_sched_barrier(0);
    }
    asm volatile("s_waitcnt vmcnt(0)");

    unsigned short* obase = Oh + ((size_t)(b * 2048 + q0 + w * 16 + ql)) * 1024 + h * 64 + kg * 4;
#pragma unroll
    for (int nv = 0; nv < 4; nv++) {
        uint2 o2 = { pack2(acco[nv][0], acco[nv][1]), pack2(acco[nv][2], acco[nv][3]) };
        *(uint2*)&obase[nv * 16] = o2;
    }
}

// ---------------------------------------------------------------------------
extern "C" void kernel_launch(void* const* d_in, const int* in_sizes, int n_in,
                              void* d_out, int out_size, void* d_ws, size_t ws_size,
                              hipStream_t stream) {
    const float* q  = (const float*)d_in[0];
    const float* k  = (const float*)d_in[1];
    const float* v  = (const float*)d_in[2];
    const float* Wq = (const float*)d_in[3];
    const float* bq = (const float*)d_in[4];
    const float* Wk = (const float*)d_in[5];
    const float* bk = (const float*)d_in[6];
    const float* Wv = (const float*)d_in[7];
    const float* bv = (const float*)d_in[8];
    const float* Wo = (const float*)d_in[9];
    const float* bo = (const float*)d_in[10];

    float* out  = (float*)d_out;                    // [2,2048,1024]
    float* attn = out + (size_t)2 * 2048 * 1024;    // [2,16,2048,2048]

    const size_t HS = 4194304;                      // 2*16*2048*64
    unsigned short* qkvb = (unsigned short*)d_ws;   // 3*HS bf16
    unsigned short* WT   = qkvb + 3 * HS;           // 4 * 1M bf16
    unsigned short* Qh   = WT + 4 * 1048576;        // [B,H,L,64]
    unsigned short* Kh   = Qh + HS;                 // [B,H,L,64]
    unsigned short* Vt   = Kh + HS;                 // [B,H,64,L]
    unsigned short* Oh   = Vt + HS;                 // [B,L,1024]

    conv_wT  <<<dim3(16, 16, 4), 256, 0, stream>>>(Wq, Wk, Wv, Wo, WT);
    conv_bf16<<<dim3(2048, 3),  256, 0, stream>>>(q, k, v, qkvb);
    gemm_qkv <<<dim3(768), 256, 0, stream>>>(qkvb, WT, bq, bk, bv, Qh, Kh, Vt);
    attn_kernel<<<dim3(512), 512, 0, stream>>>(Qh, Kh, Vt, attn, Oh);
    gemm_o   <<<dim3(256), 256, 0, stream>>>(Oh, WT + 3 * 1048576, bo, out);
}

// Round 10
// 242.171 us; speedup vs baseline: 1.3024x; 1.0007x over previous
//
#include <hip/hip_runtime.h>
#include <hip/hip_bf16.h>

typedef float f32x4 __attribute__((ext_vector_type(4)));
typedef short bf16x8 __attribute__((ext_vector_type(8)));

#define MFMA_BF16 __builtin_amdgcn_mfma_f32_16x16x32_bf16

static __device__ __forceinline__ unsigned short f2bf(float f) {
    __hip_bfloat16 h = __float2bfloat16(f);
    return __builtin_bit_cast(unsigned short, h);
}
static __device__ __forceinline__ unsigned int pack2(float a, float b) {
    return (unsigned int)f2bf(a) | ((unsigned int)f2bf(b) << 16);
}

// Async global->LDS, 16B per lane. LDS dest is wave-uniform base + lane*16.
static __device__ __forceinline__ void gl16(const unsigned short* g, unsigned short* l) {
    unsigned short* gg = const_cast<unsigned short*>(g);
    __builtin_amdgcn_global_load_lds(
        (__attribute__((address_space(1))) unsigned int*)gg,
        (__attribute__((address_space(3))) unsigned int*)l, 16, 0, 0);
}

// ---------------------------------------------------------------------------
// Prep 1: W [1024][1024] f32 (k-major) -> Wt [1024][1024] bf16 (n-major, k-contig)
// ---------------------------------------------------------------------------
__global__ __launch_bounds__(256) void conv_wT(
    const float* __restrict__ Wq, const float* __restrict__ Wk,
    const float* __restrict__ Wv, const float* __restrict__ Wo,
    unsigned short* __restrict__ WT)
{
    const int z = blockIdx.z;
    const float* W = (z == 0) ? Wq : (z == 1) ? Wk : (z == 2) ? Wv : Wo;
    unsigned short* Wt = WT + (size_t)z * 1048576;
    const int k0 = blockIdx.x * 64, n0 = blockIdx.y * 64;
    __shared__ float tl[64][68];
    const int t = threadIdx.x;
    const int r = t >> 2, cs = (t & 3) * 16;
#pragma unroll
    for (int j = 0; j < 4; j++)
        *(float4*)&tl[r][cs + j * 4] = *(const float4*)&W[(size_t)(k0 + r) * 1024 + n0 + cs + j * 4];
    __syncthreads();
    const int n = t & 63, kb = (t >> 6) * 16;
#pragma unroll
    for (int j = 0; j < 4; j++) {
        const int kk = kb + j * 4;
        uint2 o = { pack2(tl[kk][n], tl[kk + 1][n]), pack2(tl[kk + 2][n], tl[kk + 3][n]) };
        *(uint2*)&Wt[(size_t)(n0 + n) * 1024 + k0 + kk] = o;
    }
}

// ---------------------------------------------------------------------------
// Prep 2: q/k/v f32 -> bf16. grid (2048, 3).
// ---------------------------------------------------------------------------
__global__ __launch_bounds__(256) void conv_bf16(
    const float* __restrict__ q, const float* __restrict__ k, const float* __restrict__ v,
    unsigned short* __restrict__ qkvb)
{
    const int z = blockIdx.y;
    const float* s = (z == 0) ? q : (z == 1) ? k : v;
    unsigned short* d = qkvb + (size_t)z * 4194304;
    const size_t i = ((size_t)blockIdx.x * 256 + threadIdx.x) * 8;
    float4 a = *(const float4*)&s[i], b = *(const float4*)&s[i + 4];
    uint4 o = { pack2(a.x, a.y), pack2(a.z, a.w), pack2(b.x, b.y), pack2(b.z, b.w) };
    *(uint4*)&d[i] = o;
}

// ---------------------------------------------------------------------------
// Shared GEMM core v2: C(128x128) = A(row-major [M][1024] bf16) x Bt^T.
// Triple-buffered LDS, depth-2 prefetch, counted vmcnt(4) + raw barrier.
// ---------------------------------------------------------------------------
static __device__ __forceinline__ void gemm_core(
    const unsigned short* __restrict__ A, const unsigned short* __restrict__ Bt,
    unsigned short* lA, unsigned short* lB, int m0, int n0, f32x4 (&acc)[4][4])
{
    const int t = threadIdx.x;
    const int w = t >> 6, lane = t & 63, lrow = lane & 15, lkg = lane >> 4;
    const int wr = w >> 1, wc = w & 1;
    const int srow = lane >> 2, sseg = (lane & 3) * 8;

    const unsigned short* Ab0 = &A[(size_t)(m0 + w * 32 + srow) * 1024 + sseg];
    const unsigned short* Ab1 = &A[(size_t)(m0 + w * 32 + 16 + srow) * 1024 + sseg];
    const unsigned short* Bb0 = &Bt[(size_t)(n0 + w * 32 + srow) * 1024 + sseg];
    const unsigned short* Bb1 = &Bt[(size_t)(n0 + w * 32 + 16 + srow) * 1024 + sseg];

#define GISSUE(tt, buf)                                     \
    do {                                                    \
        const int k0_ = (tt) * 32;                          \
        gl16(Ab0 + k0_, &lA[(buf) * 4096 + w * 1024]);      \
        gl16(Ab1 + k0_, &lA[(buf) * 4096 + w * 1024 + 512]);\
        gl16(Bb0 + k0_, &lB[(buf) * 4096 + w * 1024]);      \
        gl16(Bb1 + k0_, &lB[(buf) * 4096 + w * 1024 + 512]);\
    } while (0)

    GISSUE(0, 0);
    GISSUE(1, 1);
    __builtin_amdgcn_sched_barrier(0);

    int bcur = 0;
    for (int tt = 0; tt < 32; ++tt) {
        if (tt < 31) { asm volatile("s_waitcnt vmcnt(4)"); }
        else         { asm volatile("s_waitcnt vmcnt(0)"); }
        __builtin_amdgcn_s_barrier();
        __builtin_amdgcn_sched_barrier(0);
        if (tt + 2 < 32) {
            int bpre = bcur + 2; if (bpre >= 3) bpre -= 3;
            GISSUE(tt + 2, bpre);
        }
        __builtin_amdgcn_sched_barrier(0);

        const unsigned short* la = &lA[bcur * 4096];
        const unsigned short* lb = &lB[bcur * 4096];
        bf16x8 af[4], bfr[4];
#pragma unroll
        for (int mi = 0; mi < 4; mi++)
            af[mi] = *(const bf16x8*)&la[(wr * 64 + mi * 16 + lrow) * 32 + lkg * 8];
#pragma unroll
        for (int ni = 0; ni < 4; ni++)
            bfr[ni] = *(const bf16x8*)&lb[(wc * 64 + ni * 16 + lrow) * 32 + lkg * 8];
        __builtin_amdgcn_s_setprio(1);
#pragma unroll
        for (int mi = 0; mi < 4; mi++)
#pragma unroll
            for (int ni = 0; ni < 4; ni++)
                acc[mi][ni] = MFMA_BF16(af[mi], bfr[ni], acc[mi][ni], 0, 0, 0);
        __builtin_amdgcn_s_setprio(0);
        bcur = (bcur == 2) ? 0 : bcur + 1;
    }
#undef GISSUE
}

// ---------------------------------------------------------------------------
// QKV projections, 1D XCD-chunked grid (768 = 8 XCD x 96).
// z=0: Q->[B,H,L,64]; z=1: K->[B,H,L,64]; z=2: V->[B,H,64,L].
// ---------------------------------------------------------------------------
__global__ __launch_bounds__(256) void gemm_qkv(
    const unsigned short* __restrict__ qkvb, const unsigned short* __restrict__ WT,
    const float* __restrict__ bq, const float* __restrict__ bk, const float* __restrict__ bv,
    unsigned short* __restrict__ Qh, unsigned short* __restrict__ Kh, unsigned short* __restrict__ Vt)
{
    const int u0 = blockIdx.x;
    const int u = (u0 & 7) * 96 + (u0 >> 3);       // XCD-contiguous chunks
    const int z = u >> 8, rm = u & 255;
    const int m0 = ((rm >> 3) & 31) * 128, n0 = (rm & 7) * 128;

    const unsigned short* A = qkvb + (size_t)z * 4194304;
    const unsigned short* Bt = WT + (size_t)z * 1048576;
    const float* bias = (z == 0) ? bq : (z == 1) ? bk : bv;

    __shared__ unsigned short lA[3 * 4096], lB[3 * 4096];
    f32x4 acc[4][4];
#pragma unroll
    for (int i = 0; i < 4; i++)
#pragma unroll
        for (int j = 0; j < 4; j++) acc[i][j] = (f32x4){0.f, 0.f, 0.f, 0.f};

    gemm_core(A, Bt, lA, lB, m0, n0, acc);

    const int t = threadIdx.x;
    const int w = t >> 6, lane = t & 63, lrow = lane & 15, lkg = lane >> 4;
    const int wr = w >> 1, wc = w & 1;

#pragma unroll
    for (int mi = 0; mi < 4; mi++) {
#pragma unroll
        for (int ni = 0; ni < 4; ni++) {
            const int gn = n0 + wc * 64 + ni * 16 + lrow;
            const float bb = bias[gn];
            const int hh = gn >> 6, dk = gn & 63;
            const int gm0 = m0 + wr * 64 + mi * 16 + lkg * 4;
            const int b2 = gm0 >> 11, ll = gm0 & 2047;
            if (z < 2) {
                unsigned short* C = (z == 0) ? Qh : Kh;
#pragma unroll
                for (int r = 0; r < 4; r++)
                    C[(size_t)((b2 * 16 + hh) * 2048 + ll + r) * 64 + dk] = f2bf(acc[mi][ni][r] + bb);
            } else {
                uint2 o = { pack2(acc[mi][ni][0] + bb, acc[mi][ni][1] + bb),
                            pack2(acc[mi][ni][2] + bb, acc[mi][ni][3] + bb) };
                *(uint2*)&Vt[(size_t)((b2 * 16 + hh) * 64 + dk) * 2048 + ll] = o;
            }
        }
    }
}

// ---------------------------------------------------------------------------
// Output projection, 1D XCD-chunked grid (256 = 8 x 32).
// ---------------------------------------------------------------------------
__global__ __launch_bounds__(256) void gemm_o(
    const unsigned short* __restrict__ Oh, const unsigned short* __restrict__ WoT,
    const float* __restrict__ bo, float* __restrict__ out)
{
    const int u0 = blockIdx.x;
    const int u = (u0 & 7) * 32 + (u0 >> 3);
    const int m0 = (u >> 3) * 128, n0 = (u & 7) * 128;

    __shared__ unsigned short lA[3 * 4096], lB[3 * 4096];
    f32x4 acc[4][4];
#pragma unroll
    for (int i = 0; i < 4; i++)
#pragma unroll
        for (int j = 0; j < 4; j++) acc[i][j] = (f32x4){0.f, 0.f, 0.f, 0.f};

    gemm_core(Oh, WoT, lA, lB, m0, n0, acc);

    const int t = threadIdx.x;
    const int w = t >> 6, lane = t & 63, lrow = lane & 15, lkg = lane >> 4;
    const int wr = w >> 1, wc = w & 1;

#pragma unroll
    for (int mi = 0; mi < 4; mi++) {
#pragma unroll
        for (int ni = 0; ni < 4; ni++) {
            const int gn = n0 + wc * 64 + ni * 16 + lrow;
            const float bb = bo[gn];
            const int gm0 = m0 + wr * 64 + mi * 16 + lkg * 4;
#pragma unroll
            for (int r = 0; r < 4; r++)
                out[(size_t)(gm0 + r) * 1024 + gn] = acc[mi][ni][r] + bb;
        }
    }
}

// ---------------------------------------------------------------------------
// Fused attention v3: Q-tile 64, 4 waves (256 thr), 1024 blocks -> 4/CU.
// LDS 32KB: regA 16KB (sweep1 K dbuf [2][4096]sh; sweep2 f32 P-stage) +
// kv 16KB (sweep2 single K[64][64] + V[64][64] buffer).
// Sweep 1: KVBLK=64 dbuf, MFMA cluster + exp2 row sums; last tile prefetches
// sweep-2 tile 0 into kv. Sweep 2 per tile: QK -> exp->stage -> PV ->
// barrier1 (kv free) -> issue loads(t+1) -> transposed 256B nt-stores ->
// vmcnt(4) (retires loads, keeps 4 stores in flight) -> barrier2.
// Load latency covered by the other 3 resident blocks.
// ---------------------------------------------------------------------------
__global__ __launch_bounds__(256, 4) void attn_kernel(
    const unsigned short* __restrict__ Qh, const unsigned short* __restrict__ Kh,
    const unsigned short* __restrict__ Vt, float* __restrict__ attn,
    unsigned short* __restrict__ Oh)
{
    const int bid = blockIdx.x;
    const int swz = (bid & 7) * 128 + (bid >> 3);    // XCD-contiguous (1024 = 8*128)
    const int bh = swz >> 5;
    const int q0 = (swz & 31) * 64;
    const int b = bh >> 4, h = bh & 15;
    const int t = threadIdx.x;
    const int w = t >> 6, lane = t & 63, ql = lane & 15, kg = lane >> 4;

    __shared__ unsigned short regA[8192];    // 16KB: sweep1 K dbuf / sweep2 f32 stage
    __shared__ unsigned short kv[8192];      // 16KB: sweep2 K (0..4095) + V (4096..)

    const size_t kvbase = (size_t)bh * 2048 * 64;
    const float C = 0.18033688011112042f;    // 0.125 * log2(e)

    const unsigned short* qptr = Qh + kvbase + (size_t)(q0 + w * 16 + ql) * 64 + kg * 8;
    const bf16x8 qf0 = *(const bf16x8*)(qptr);
    const bf16x8 qf1 = *(const bf16x8*)(qptr + 32);

    const unsigned short* Kbh = Kh + kvbase;
    const unsigned short* Vbh = Vt + kvbase;

    // staging: wave w covers 16 rows (2x gl16 of 8 rows); source col16 pre-swizzled
    const int kr = w * 16 + (lane >> 3);             // rows kr, kr+8
    const int kc = (lane & 7) ^ (kr & 7);            // same for kr and kr+8
    const int r7 = ql & 7;

    // ---- sweep 1: denominators (K tiles of 64 rows, double-buffered) ----
    f32x4 ls4 = (f32x4){0.f, 0.f, 0.f, 0.f};
    {
        gl16(Kbh + (size_t)kr * 64 + kc * 8, &regA[w * 1024]);
        gl16(Kbh + (size_t)(kr + 8) * 64 + kc * 8, &regA[w * 1024 + 512]);
        __syncthreads();
        for (int kt = 0; kt < 32; ++kt) {
            const int c = kt & 1;
            if (kt < 31) {
                const int k0n = (kt + 1) * 64;
                gl16(Kbh + (size_t)(k0n + kr) * 64 + kc * 8, &regA[(c ^ 1) * 4096 + w * 1024]);
                gl16(Kbh + (size_t)(k0n + kr + 8) * 64 + kc * 8, &regA[(c ^ 1) * 4096 + w * 1024 + 512]);
            } else {
                // prefetch sweep-2 tile 0 into kv (K rows + V rows)
                gl16(Kbh + (size_t)kr * 64 + kc * 8, &kv[w * 1024]);
                gl16(Kbh + (size_t)(kr + 8) * 64 + kc * 8, &kv[w * 1024 + 512]);
                gl16(Vbh + (size_t)kr * 2048 + kc * 8, &kv[4096 + w * 1024]);
                gl16(Vbh + (size_t)(kr + 8) * 2048 + kc * 8, &kv[4096 + w * 1024 + 512]);
            }
            const unsigned short* Kl = &regA[c * 4096];
            f32x4 sacc[4];
            __builtin_amdgcn_s_setprio(1);
#pragma unroll
            for (int ni = 0; ni < 4; ni++) {
                const int rb = (ni * 16 + ql) * 64;
                bf16x8 kf0 = *(const bf16x8*)&Kl[rb + ((kg ^ r7) * 8)];
                bf16x8 kf1 = *(const bf16x8*)&Kl[rb + (((4 + kg) ^ r7) * 8)];
                f32x4 s = (f32x4){0.f, 0.f, 0.f, 0.f};
                s = MFMA_BF16(kf0, qf0, s, 0, 0, 0);
                sacc[ni] = MFMA_BF16(kf1, qf1, s, 0, 0, 0);
            }
            __builtin_amdgcn_s_setprio(0);
#pragma unroll
            for (int ni = 0; ni < 4; ni++)
#pragma unroll
                for (int r = 0; r < 4; r++) ls4[r] += exp2f(sacc[ni][r] * C);
            __syncthreads();
        }
    }
    float lsum = ls4[0] + ls4[1] + ls4[2] + ls4[3];
    lsum += __shfl_xor(lsum, 16);
    lsum += __shfl_xor(lsum, 32);
    const float mlg = -log2f(lsum);          // p = exp2(S*C - log2 l)

    // ---- sweep 2: attn write + PV (K+V tiles of 64, single kv buffer) ----
    f32x4 acco[4];
#pragma unroll
    for (int nv = 0; nv < 4; nv++) acco[nv] = (f32x4){0.f, 0.f, 0.f, 0.f};

    float* stgW = (float*)regA + w * 1024;   // per-wave [16 q][64 k] f32 stage
    const unsigned short* kvK = kv;
    const unsigned short* kvV = kv + 4096;
    float* abase = attn + ((size_t)bh * 2048 + q0 + w * 16) * 2048 + ql * 4;

    for (int kt = 0; kt < 32; ++kt) {
        const int k0 = kt * 64;

        // QK^T cluster (reads kvK)
        f32x4 sacc[4];
        __builtin_amdgcn_s_setprio(1);
#pragma unroll
        for (int ni = 0; ni < 4; ni++) {
            const int rb = (ni * 16 + ql) * 64;
            bf16x8 kf0 = *(const bf16x8*)&kvK[rb + ((kg ^ r7) * 8)];
            bf16x8 kf1 = *(const bf16x8*)&kvK[rb + (((4 + kg) ^ r7) * 8)];
            f32x4 s = (f32x4){0.f, 0.f, 0.f, 0.f};
            s = MFMA_BF16(kf0, qf0, s, 0, 0, 0);
            sacc[ni] = MFMA_BF16(kf1, qf1, s, 0, 0, 0);
        }
        __builtin_amdgcn_s_setprio(0);

        // exp -> f32 stage (wave-private)
#pragma unroll
        for (int ni = 0; ni < 4; ni++) {
            f32x4 p;
#pragma unroll
            for (int r = 0; r < 4; r++) p[r] = exp2f(fmaf(sacc[ni][r], C, mlg));
            *(f32x4*)&stgW[ql * 64 + ni * 16 + kg * 4] = p;
        }

        // PV: derive bf16 P from stage; O^T += V^T x P^T (reads kvV)
        __builtin_amdgcn_s_setprio(1);
#pragma unroll
        for (int s4 = 0; s4 < 2; s4++) {
            const float* ps = &stgW[ql * 64 + s4 * 32 + kg * 8];
            f32x4 pa = *(const f32x4*)ps;
            f32x4 pb = *(const f32x4*)(ps + 4);
            uint4 pw = { pack2(pa[0], pa[1]), pack2(pa[2], pa[3]),
                         pack2(pb[0], pb[1]), pack2(pb[2], pb[3]) };
            bf16x8 pf = __builtin_bit_cast(bf16x8, pw);
#pragma unroll
            for (int nv = 0; nv < 4; nv++) {
                const int cc = (s4 * 4 + kg) ^ r7;
                bf16x8 vf = *(const bf16x8*)&kvV[(nv * 16 + ql) * 64 + cc * 8];
                acco[nv] = MFMA_BF16(vf, pf, acco[nv], 0, 0, 0);
            }
        }
        __builtin_amdgcn_s_setprio(0);

        // barrier 1: all waves done reading kv
        __builtin_amdgcn_s_barrier();
        __builtin_amdgcn_sched_barrier(0);

        // issue next tile's loads (older than the stores below)
        if (kt < 31) {
            const int k0n = (kt + 1) * 64;
            gl16(Kbh + (size_t)(k0n + kr) * 64 + kc * 8, &kv[w * 1024]);
            gl16(Kbh + (size_t)(k0n + kr + 8) * 64 + kc * 8, &kv[w * 1024 + 512]);
            gl16(Vbh + (size_t)kr * 2048 + k0n + kc * 8, &kv[4096 + w * 1024]);
            gl16(Vbh + (size_t)(kr + 8) * 2048 + k0n + kc * 8, &kv[4096 + w * 1024 + 512]);
        }
        __builtin_amdgcn_sched_barrier(0);

        // transposed attn stores (4 instrs, 4 rows x 256B contiguous each)
#pragma unroll
        for (int i = 0; i < 4; i++) {
            const int row = i * 4 + kg;
            f32x4 vv = *(const f32x4*)&stgW[row * 64 + ql * 4];
            __builtin_nontemporal_store(vv, (f32x4*)&abase[(size_t)row * 2048 + k0]);
        }

        // retire the loads (and anything older), keep this tile's 4 stores
        asm volatile("s_waitcnt vmcnt(4)");
        __builtin_amdgcn_s_barrier();        // barrier 2: all waves' loads landed
        __builtin_amdgcn_sched_barrier(0);
    }
    asm volatile("s_waitcnt vmcnt(0)");

    unsigned short* obase = Oh + ((size_t)(b * 2048 + q0 + w * 16 + ql)) * 1024 + h * 64 + kg * 4;
#pragma unroll
    for (int nv = 0; nv < 4; nv++) {
        uint2 o2 = { pack2(acco[nv][0], acco[nv][1]), pack2(acco[nv][2], acco[nv][3]) };
        *(uint2*)&obase[nv * 16] = o2;
    }
}

// ---------------------------------------------------------------------------
extern "C" void kernel_launch(void* const* d_in, const int* in_sizes, int n_in,
                              void* d_out, int out_size, void* d_ws, size_t ws_size,
                              hipStream_t stream) {
    const float* q  = (const float*)d_in[0];
    const float* k  = (const float*)d_in[1];
    const float* v  = (const float*)d_in[2];
    const float* Wq = (const float*)d_in[3];
    const float* bq = (const float*)d_in[4];
    const float* Wk = (const float*)d_in[5];
    const float* bk = (const float*)d_in[6];
    const float* Wv = (const float*)d_in[7];
    const float* bv = (const float*)d_in[8];
    const float* Wo = (const float*)d_in[9];
    const float* bo = (const float*)d_in[10];

    float* out  = (float*)d_out;                    // [2,2048,1024]
    float* attn = out + (size_t)2 * 2048 * 1024;    // [2,16,2048,2048]

    const size_t HS = 4194304;                      // 2*16*2048*64
    unsigned short* qkvb = (unsigned short*)d_ws;   // 3*HS bf16
    unsigned short* WT   = qkvb + 3 * HS;           // 4 * 1M bf16
    unsigned short* Qh   = WT + 4 * 1048576;        // [B,H,L,64]
    unsigned short* Kh   = Qh + HS;                 // [B,H,L,64]
    unsigned short* Vt   = Kh + HS;                 // [B,H,64,L]
    unsigned short* Oh   = Vt + HS;                 // [B,L,1024]

    conv_wT  <<<dim3(16, 16, 4), 256, 0, stream>>>(Wq, Wk, Wv, Wo, WT);
    conv_bf16<<<dim3(2048, 3),  256, 0, stream>>>(q, k, v, qkvb);
    gemm_qkv <<<dim3(768), 256, 0, stream>>>(qkvb, WT, bq, bk, bv, Qh, Kh, Vt);
    attn_kernel<<<dim3(1024), 256, 0, stream>>>(Qh, Kh, Vt, attn, Oh);
    gemm_o   <<<dim3(256), 256, 0, stream>>>(Oh, WT + 3 * 1048576, bo, out);
}